// Round 9
// baseline (794.101 us; speedup 1.0000x reference)
//
#include <hip/hip_runtime.h>

typedef unsigned int u32;
typedef unsigned short u16;
typedef __attribute__((ext_vector_type(8))) short bf16x8;
typedef __attribute__((ext_vector_type(4))) float f32x4;

#define Bb 4
#define Nn 50000
#define Dd 128
#define Rr 200
#define BN (Bb*Nn)
#define MAXDEG 16
#define LDW 136          // u16 row stride inside a wave slab (272 B, 16B-aligned)
#define SLAB 2176        // u16 per wave slab: 1 tile x 16 rows x 136 (hi plane only)
#define HROW 256         // u16 per combined hh row: [hs 128 | hidden 128]

// ---------- scalar helpers ----------
__device__ __forceinline__ float bfs(u16 u) { return __uint_as_float(((u32)u) << 16); }
__device__ __forceinline__ float bflo(u32 u) { return __uint_as_float(u << 16); }
__device__ __forceinline__ float bfhi(u32 u) { return __uint_as_float(u & 0xffff0000u); }
__device__ __forceinline__ u16 f2bf(float f) {
    u32 x = __float_as_uint(f);
    return (u16)((x + 0x7fffu + ((x >> 16) & 1u)) >> 16);
}
template<bool BF>
__device__ __forceinline__ float ld1(const void* p, int i) {
    if (BF) return bfs(((const u16*)p)[i]);
    else    return ((const float*)p)[i];
}

// ---------- dtype probe: bf16-packed vs f32 ----------
__global__ void k_probe(const u32* __restrict__ q, int* __restrict__ flag) {
    int t = threadIdx.x;
    u32 w = q[t];
    int e = (int)((w >> 7) & 0xffu);
    bool plaus = (e >= 100 && e <= 150);
    unsigned long long m = __ballot(plaus);
    if (t == 0) flag[0] = (__popcll(m) >= 56) ? 1 : 0;
}

// ---------- prep: split weights to bf16 hi/lo, f32 copies of small tensors ----------
__global__ __launch_bounds__(256) void k_wprep(
    const void* Ws, const void* w1, const void* w2,
    const void* b1, const void* b2, const void* wattn, const void* rela,
    u16* WsH, u16* WsL, u16* w1H, u16* w1L, u16* w2H, u16* w2L,
    float* b1f, float* b2f, float* wattnf, float* relaf, const int* flag) {
    bool bf = (*flag != 0);
    int i = blockIdx.x * 256 + threadIdx.x;
    if (i < 16384) {
        float x = bf ? bfs(((const u16*)Ws)[i]) : ((const float*)Ws)[i];
        u16 h = f2bf(x); WsH[i] = h; WsL[i] = f2bf(x - bfs(h));
    } else if (i < 32768) {
        int j = i - 16384;
        float x = bf ? bfs(((const u16*)w1)[j]) : ((const float*)w1)[j];
        u16 h = f2bf(x); w1H[j] = h; w1L[j] = f2bf(x - bfs(h));
    } else if (i < 49152) {
        int j = i - 32768;
        float x = bf ? bfs(((const u16*)w2)[j]) : ((const float*)w2)[j];
        u16 h = f2bf(x); w2H[j] = h; w2L[j] = f2bf(x - bfs(h));
    } else if (i < 49152 + 128) {
        int j = i - 49152;
        b1f[j] = bf ? bfs(((const u16*)b1)[j]) : ((const float*)b1)[j];
    } else if (i < 49152 + 256) {
        int j = i - 49152 - 128;
        b2f[j] = bf ? bfs(((const u16*)b2)[j]) : ((const float*)b2)[j];
    } else if (i < 49152 + 384) {
        int j = i - 49152 - 256;
        wattnf[j] = bf ? bfs(((const u16*)wattn)[j]) : ((const float*)wattn)[j];
    } else if (i < 49152 + 384 + 25600) {
        int j = i - 49152 - 384;
        relaf[j] = bf ? bfs(((const u16*)rela)[j]) : ((const float*)rela)[j];
    }
}

// ---------- wrq[b*R+r][a] = Wr.rela_r + Wqr.query_b + bias (tiny, f32 VALU) ----------
template<bool BF>
__device__ __forceinline__ float dotrow1(const void* W, int row, const float* s) {
    float acc = 0.f;
    if (BF) {
        const uint4* wv = (const uint4*)((const u16*)W + row * Dd);
#pragma unroll
        for (int k = 0; k < 16; k++) {
            uint4 u = wv[k];
            acc += bflo(u.x)*s[k*8+0] + bfhi(u.x)*s[k*8+1]
                 + bflo(u.y)*s[k*8+2] + bfhi(u.y)*s[k*8+3]
                 + bflo(u.z)*s[k*8+4] + bfhi(u.z)*s[k*8+5]
                 + bflo(u.w)*s[k*8+6] + bfhi(u.w)*s[k*8+7];
        }
    } else {
        const float4* wv = (const float4*)((const float*)W + row * Dd);
#pragma unroll
        for (int k = 0; k < 32; k++) {
            float4 u = wv[k];
            acc += u.x*s[4*k] + u.y*s[4*k+1] + u.z*s[4*k+2] + u.w*s[4*k+3];
        }
    }
    return acc;
}
template<bool BF>
__device__ void k_wrq_body(const void* Wr, const void* Wqr, const void* bias,
                           const void* rela, const void* query, float* wrq, float* s) {
    int br = blockIdx.x;
    int b = br / Rr, r = br % Rr;
    int a = threadIdx.x;
    s[a]      = ld1<BF>(rela,  r * Dd + a);
    s[Dd + a] = ld1<BF>(query, b * Dd + a);
    __syncthreads();
    wrq[br * Dd + a] = ld1<BF>(bias, a) + dotrow1<BF>(Wr, a, s) + dotrow1<BF>(Wqr, a, s + Dd);
}
__global__ __launch_bounds__(128) void k_wrq(const void* Wr, const void* Wqr, const void* bias,
                                             const void* rela, const void* query, float* wrq,
                                             const int* flag) {
    __shared__ float s[2 * Dd];
    if (*flag) k_wrq_body<true>(Wr, Wqr, bias, rela, query, wrq, s);
    else       k_wrq_body<false>(Wr, Wqr, bias, rela, query, wrq, s);
}

// ---------- k_hs: hh[node] = [ hidden@Ws^T (bf16 x128) | hidden (bf16 x128) ] ----------
template<bool BF>
__device__ void hs_body(const void* hidden, const u16* WsH, const u16* WsL, u16* hh,
                        u16* __restrict__ Smh) {
    int t = threadIdx.x, lane = t & 63;
    int m16 = lane & 15, quad = lane >> 4;
    int w = t >> 6;
    int base = blockIdx.x * 64 + w * 16;
    u16* Sml = Smh + 16 * LDW;

    if (BF) {
        const u16* src = (const u16*)hidden + (size_t)base * Dd;
#pragma unroll
        for (int j = 0; j < 4; j++) {
            int flat = j * 64 + lane;            // 256 chunks of 8 u16
            int row = flat >> 4, c8 = (flat & 15) * 8;
            uint4 v = ((const uint4*)src)[flat];
            *(uint4*)(Smh + row * LDW + c8) = v;
            // hidden copy into combined row (bytes [256,512))
            *(uint4*)(hh + (size_t)(base + row) * HROW + 128 + c8) = v;
        }
    } else {
        const float* src = (const float*)hidden + (size_t)base * Dd;
#pragma unroll
        for (int j = 0; j < 8; j++) {
            int flat = j * 64 + lane;            // 512 float4 chunks
            int row = flat >> 5, c4 = (flat & 31) * 4;
            float4 v = ((const float4*)src)[flat];
            u16 h0 = f2bf(v.x), h1 = f2bf(v.y), h2 = f2bf(v.z), h3 = f2bf(v.w);
            ushort4 hv; hv.x = h0; hv.y = h1; hv.z = h2; hv.w = h3;
            ushort4 lv; lv.x = f2bf(v.x - bfs(h0)); lv.y = f2bf(v.y - bfs(h1));
                        lv.z = f2bf(v.z - bfs(h2)); lv.w = f2bf(v.w - bfs(h3));
            *(ushort4*)(Smh + row * LDW + c4) = hv;
            *(ushort4*)(Sml + row * LDW + c4) = lv;
            *(ushort4*)(hh + (size_t)(base + row) * HROW + 128 + c4) = hv; // unused by f32 gather
        }
    }
    const u16* ph = Smh + m16 * LDW + quad * 8;
    const u16* pl = Sml + m16 * LDW + quad * 8;
    bf16x8 ah[4], al[4];
#pragma unroll
    for (int ks = 0; ks < 4; ks++) {
        ah[ks] = *(const bf16x8*)(ph + ks * 32);
        if (!BF) al[ks] = *(const bf16x8*)(pl + ks * 32);
    }
#pragma unroll
    for (int nt = 0; nt < 8; nt++) {
        int n = nt * 16 + m16;
        f32x4 acc = {0.f, 0.f, 0.f, 0.f};
#pragma unroll
        for (int ks = 0; ks < 4; ks++) {
            bf16x8 bh = *(const bf16x8*)(WsH + n * Dd + ks * 32 + quad * 8);
            acc = __builtin_amdgcn_mfma_f32_16x16x32_bf16(ah[ks], bh, acc, 0, 0, 0);
            if (!BF) {
                bf16x8 bl = *(const bf16x8*)(WsL + n * Dd + ks * 32 + quad * 8);
                acc = __builtin_amdgcn_mfma_f32_16x16x32_bf16(al[ks], bh, acc, 0, 0, 0);
                acc = __builtin_amdgcn_mfma_f32_16x16x32_bf16(ah[ks], bl, acc, 0, 0, 0);
            }
        }
#pragma unroll
        for (int r = 0; r < 4; r++)
            hh[(size_t)(base + quad * 4 + r) * HROW + n] = f2bf(acc[r]);
    }
}
__global__ __launch_bounds__(256, 4) void k_hs(const void* hidden, const u16* WsH,
                                               const u16* WsL, u16* hh, const int* flag) {
    __shared__ __align__(16) u16 SL[4][2 * SLAB];   // k_hs keeps hi+lo planes (f32 path)
    u16* slab = SL[threadIdx.x >> 6];
    if (*flag) hs_body<true>(hidden, WsH, WsL, hh, slab);
    else       hs_body<false>(hidden, WsH, WsL, hh, slab);
}

// ---------- counting-sort scatter: packed rec ----------
__global__ __launch_bounds__(256) void k_scatter(const int* __restrict__ edges,
                                                 u32* __restrict__ slots,
                                                 int* __restrict__ deg, int nE) {
    int i = blockIdx.x * 256 + threadIdx.x;
    if (i >= nE) return;
    int bat = edges[4*i], sub = edges[4*i+1], rel = edges[4*i+2], obj = edges[4*i+3];
    int pos = atomicAdd(&deg[obj], 1);
    if (pos < MAXDEG)
        slots[(size_t)obj * MAXDEG + pos] = (u32)sub | ((u32)rel << 18) | ((u32)bat << 26);
}

// ---------- fused: one-pass gather (alpha inline) -> hi-only slab -> 2-layer MFMA MLP ----------
template<bool BF>
__device__ __forceinline__ void epre(u32 rec, int lane, float2 wa,
                                     const u16* __restrict__ hh,
                                     const float* __restrict__ wrq,
                                     const void* __restrict__ hidden,
                                     const float* __restrict__ relaf,
                                     float& p, float& x, float& y) {
    int sub = rec & 0x3FFFF, rel = (rec >> 18) & 0xFF, bat = (int)(rec >> 26);
    const u16* row = hh + (size_t)sub * HROW;
    u32 hp = ((const u32*)row)[lane];                      // hs pair
    float2 wq = ((const float2*)wrq)[(bat * Rr + rel) * 64 + lane];
    float2 mr = ((const float2*)relaf)[rel * 64 + lane];
    float mh0, mh1;
    if (BF) {
        u32 mh = ((const u32*)(row + 128))[lane];          // hidden pair, same 512B row
        mh0 = bflo(mh); mh1 = bfhi(mh);
    } else {
        float2 mh = ((const float2*)hidden)[(size_t)sub * 64 + lane];
        mh0 = mh.x; mh1 = mh.y;
    }
    float h0 = fmaxf(bflo(hp) + wq.x, 0.f);
    float h1 = fmaxf(bfhi(hp) + wq.y, 0.f);
    p = h0 * wa.x + h1 * wa.y;
    x = mh0 * mr.x;
    y = mh1 * mr.y;
}

__device__ __forceinline__ float sigm(float p) { return 1.f / (1.f + __expf(-p)); }

template<bool BF>
__device__ void fused_body(const u32* __restrict__ slots, const int* __restrict__ deg,
                           const u16* __restrict__ hh, const float* __restrict__ wrq,
                           const float* __restrict__ wattnf,
                           const void* __restrict__ hidden, const float* __restrict__ relaf,
                           const u16* w1H, const u16* w1L, const u16* w2H, const u16* w2L,
                           const float* b1f, const float* b2f, void* out,
                           u16* __restrict__ Smh, u32* __restrict__ SB) {
    int t = threadIdx.x, lane = t & 63;
    int m16 = lane & 15, quad = lane >> 4;
    int w = t >> 6;
    int base = blockIdx.x * 64 + w * 16;
    float2 wa = ((const float2*)wattnf)[lane];

    // ---- stage first-8 recs of all 16 nodes into LDS: one dwordx2/lane ----
    {
        int f = lane * 2;                 // flat u32 index, 128 total
        int nd = f >> 3, e0 = f & 7;      // node, even edge
        uint2 v = *(const uint2*)(slots + (size_t)(base + nd) * MAXDEG + e0);
        *(uint2*)(SB + nd * 8 + e0) = v;
    }
    // same-wave RAW on LDS; compiler inserts lgkmcnt before first read

    // ---- gather: node pairs, 8-wide groups, fused butterfly, inline alpha ----
    for (int i = 0; i < 16; i += 2) {
        int nA = base + i, nB = nA + 1;
        int dA = deg[nA]; if (dA > MAXDEG) dA = MAXDEG;
        int dB = deg[nB]; if (dB > MAXDEG) dB = MAXDEG;
        const u32* rA = SB + i * 8;
        const u32* rB = rA + 8;
        float aA0 = 0.f, aA1 = 0.f, aB0 = 0.f, aB1 = 0.f;

#pragma unroll
        for (int g = 0; g < 2; g++) {
            int eo = g * 4;
            if (g == 1 && dA <= 4 && dB <= 4) break;   // wave-uniform skip
            float p[8], x[8], y[8], mk[8];
#pragma unroll
            for (int e = 0; e < 4; e++) {
                int ee = eo + e;
                u32 ra = (ee < dA) ? rA[ee] : 0u;
                u32 rb = (ee < dB) ? rB[ee] : 0u;
                mk[2*e]   = (ee < dA) ? 1.f : 0.f;
                mk[2*e+1] = (ee < dB) ? 1.f : 0.f;
                epre<BF>(ra, lane, wa, hh, wrq, hidden, relaf, p[2*e],   x[2*e],   y[2*e]);
                epre<BF>(rb, lane, wa, hh, wrq, hidden, relaf, p[2*e+1], x[2*e+1], y[2*e+1]);
            }
#pragma unroll
            for (int m = 32; m >= 1; m >>= 1) {
                float s0 = __shfl_xor(p[0], m), s1 = __shfl_xor(p[1], m);
                float s2 = __shfl_xor(p[2], m), s3 = __shfl_xor(p[3], m);
                float s4 = __shfl_xor(p[4], m), s5 = __shfl_xor(p[5], m);
                float s6 = __shfl_xor(p[6], m), s7 = __shfl_xor(p[7], m);
                p[0] += s0; p[1] += s1; p[2] += s2; p[3] += s3;
                p[4] += s4; p[5] += s5; p[6] += s6; p[7] += s7;
            }
#pragma unroll
            for (int e = 0; e < 4; e++) {
                float la = sigm(p[2*e])   * mk[2*e];
                float lb = sigm(p[2*e+1]) * mk[2*e+1];
                aA0 += x[2*e]   * la; aA1 += y[2*e]   * la;
                aB0 += x[2*e+1] * lb; aB1 += y[2*e+1] * lb;
            }
        }
        // rare tails (deg > 8) straight from global slots
        for (int e = 8; e < dA; e++) {
            u32 r0 = slots[(size_t)nA * MAXDEG + e];
            float p0, x0, y0;
            epre<BF>(r0, lane, wa, hh, wrq, hidden, relaf, p0, x0, y0);
#pragma unroll
            for (int m = 32; m >= 1; m >>= 1) p0 += __shfl_xor(p0, m);
            float l0 = sigm(p0);
            aA0 += x0 * l0; aA1 += y0 * l0;
        }
        for (int e = 8; e < dB; e++) {
            u32 r0 = slots[(size_t)nB * MAXDEG + e];
            float p0, x0, y0;
            epre<BF>(r0, lane, wa, hh, wrq, hidden, relaf, p0, x0, y0);
#pragma unroll
            for (int m = 32; m >= 1; m >>= 1) p0 += __shfl_xor(p0, m);
            float l0 = sigm(p0);
            aB0 += x0 * l0; aB1 += y0 * l0;
        }

        // hi-plane only (agg rounded to bf16; ~2^-9 rel, within absmax budget)
        u16 hA0 = f2bf(aA0), hA1 = f2bf(aA1);
        *(u32*)(Smh + i * LDW + 2 * lane) = (u32)hA0 | ((u32)hA1 << 16);
        u16 hB0 = f2bf(aB0), hB1 = f2bf(aB1);
        *(u32*)(Smh + (i + 1) * LDW + 2 * lane) = (u32)hB0 | ((u32)hB1 << 16);
    }

    // ---- layer 1: mid = agg @ W1^T + b1 (hi-only A-frags) ----
    const u16* ph = Smh + m16 * LDW + quad * 8;
    bf16x8 ah[4];
#pragma unroll
    for (int ks = 0; ks < 4; ks++)
        ah[ks] = *(const bf16x8*)(ph + ks * 32);
#pragma unroll
    for (int nt = 0; nt < 8; nt++) {
        int n = nt * 16 + m16;
        f32x4 acc = {0.f, 0.f, 0.f, 0.f};
#pragma unroll
        for (int ks = 0; ks < 4; ks++) {
            bf16x8 bh = *(const bf16x8*)(w1H + n * Dd + ks * 32 + quad * 8);
            acc = __builtin_amdgcn_mfma_f32_16x16x32_bf16(ah[ks], bh, acc, 0, 0, 0);
            if (!BF) {
                bf16x8 bl = *(const bf16x8*)(w1L + n * Dd + ks * 32 + quad * 8);
                acc = __builtin_amdgcn_mfma_f32_16x16x32_bf16(ah[ks], bl, acc, 0, 0, 0);
            }
        }
        float bv = b1f[n];
#pragma unroll
        for (int r = 0; r < 4; r++) {
            float v = acc[r] + bv;
            int row = quad * 4 + r;
            Smh[row * LDW + n] = f2bf(v);
        }
    }

    // ---- layer 2: out = relu(mid @ W2^T + b2), masked by deg ----
    bf16x8 mh[4];
#pragma unroll
    for (int ks = 0; ks < 4; ks++)
        mh[ks] = *(const bf16x8*)(ph + ks * 32);
    int dg[4];
#pragma unroll
    for (int r = 0; r < 4; r++) dg[r] = deg[base + quad * 4 + r];
#pragma unroll
    for (int nt = 0; nt < 8; nt++) {
        int n = nt * 16 + m16;
        f32x4 acc = {0.f, 0.f, 0.f, 0.f};
#pragma unroll
        for (int ks = 0; ks < 4; ks++) {
            bf16x8 bh = *(const bf16x8*)(w2H + n * Dd + ks * 32 + quad * 8);
            acc = __builtin_amdgcn_mfma_f32_16x16x32_bf16(mh[ks], bh, acc, 0, 0, 0);
            if (!BF) {
                bf16x8 bl = *(const bf16x8*)(w2L + n * Dd + ks * 32 + quad * 8);
                acc = __builtin_amdgcn_mfma_f32_16x16x32_bf16(mh[ks], bl, acc, 0, 0, 0);
            }
        }
        float bv = b2f[n];
#pragma unroll
        for (int r = 0; r < 4; r++) {
            float v = fmaxf(acc[r] + bv, 0.f);
            if (dg[r] == 0) v = 0.f;
            size_t o = (size_t)(base + quad * 4 + r) * Dd + n;
            if (BF) ((u16*)out)[o] = f2bf(v);
            else    ((float*)out)[o] = v;
        }
    }
}
__global__ __launch_bounds__(256, 8) void k_fused(const u32* slots, const int* deg,
                                                  const u16* hh, const float* wrq,
                                                  const float* wattnf, const void* hidden,
                                                  const float* relaf,
                                                  const u16* w1H, const u16* w1L,
                                                  const u16* w2H, const u16* w2L,
                                                  const float* b1f, const float* b2f,
                                                  void* out, const int* flag) {
    __shared__ __align__(16) u16 SL[4][SLAB];        // 17408 B
    __shared__ __align__(16) u32 SBL[4][128];        //  2048 B  -> 19456 B/block, 8 blocks/CU
    int w = threadIdx.x >> 6;
    if (*flag) fused_body<true>(slots, deg, hh, wrq, wattnf, hidden, relaf,
                                w1H, w1L, w2H, w2L, b1f, b2f, out, SL[w], SBL[w]);
    else       fused_body<false>(slots, deg, hh, wrq, wattnf, hidden, relaf,
                                 w1H, w1L, w2H, w2L, b1f, b2f, out, SL[w], SBL[w]);
}

extern "C" void kernel_launch(void* const* d_in, const int* in_sizes, int n_in,
                              void* d_out, int out_size, void* d_ws, size_t ws_size,
                              hipStream_t stream) {
    const void* query  = d_in[0];
    const void* hidden = d_in[3];
    const int*  edges  = (const int*)d_in[4];
    const void* Ws     = d_in[6];
    const void* Wr     = d_in[7];
    const void* Wqr    = d_in[8];
    const void* Wqrb   = d_in[9];
    const void* Wattn  = d_in[10];
    const void* rela   = d_in[11];
    const void* w1     = d_in[12];
    const void* b1     = d_in[13];
    const void* w2     = d_in[14];
    const void* b2     = d_in[15];

    char* ws = (char*)d_ws;
    u16*   hh     = (u16*)ws;                        // 102,400,000 B (200k x 512B combined)
    float* wrq    = (float*)(ws + 102400000);        //     409,600 B
    u32*   slots  = (u32*) (ws + 102809600);         //  12,800,000 B (200k x 16 recs)
    int*   deg    = (int*) (ws + 115609600);         //     800,000 B
    u16*   WsH    = (u16*) (ws + 116409600);
    u16*   WsL    = (u16*) (ws + 116442368);
    u16*   w1H    = (u16*) (ws + 116475136);
    u16*   w1L    = (u16*) (ws + 116507904);
    u16*   w2H    = (u16*) (ws + 116540672);
    u16*   w2L    = (u16*) (ws + 116573440);
    float* b1f    = (float*)(ws + 116606208);
    float* b2f    = (float*)(ws + 116606720);
    float* wattnf = (float*)(ws + 116607232);
    float* relaf  = (float*)(ws + 116607744);        //     102,400 B
    int*   flag   = (int*) (ws + 116710144);

    int nE = in_sizes[4] / 4;

    k_probe<<<1, 64, 0, stream>>>((const u32*)query, flag);
    hipMemsetAsync(deg, 0, (size_t)BN * 4, stream);
    k_wprep<<<294, 256, 0, stream>>>(Ws, w1, w2, b1, b2, Wattn, rela,
                                     WsH, WsL, w1H, w1L, w2H, w2L,
                                     b1f, b2f, wattnf, relaf, flag);
    k_wrq<<<Bb * Rr, 128, 0, stream>>>(Wr, Wqr, Wqrb, rela, query, wrq, flag);
    k_hs<<<BN / 64, 256, 0, stream>>>(hidden, WsH, WsL, hh, flag);
    k_scatter<<<(nE + 255) / 256, 256, 0, stream>>>(edges, slots, deg, nE);
    k_fused<<<BN / 64, 256, 0, stream>>>(slots, deg, hh, wrq, wattnf, hidden, relaf,
                                         w1H, w1L, w2H, w2L, b1f, b2f, d_out, flag);
}

// Round 10
// 721.422 us; speedup vs baseline: 1.1007x; 1.1007x over previous
//
#include <hip/hip_runtime.h>

typedef unsigned int u32;
typedef unsigned short u16;
typedef __attribute__((ext_vector_type(8))) short bf16x8;
typedef __attribute__((ext_vector_type(4))) float f32x4;

#define Bb 4
#define Nn 50000
#define Dd 128
#define Rr 200
#define BN (Bb*Nn)
#define MAXDEG 16
#define LDW 136          // u16 row stride inside a wave slab (272 B, 16B-aligned)
#define SLAB 2176        // u16 per wave slab: 1 tile x 16 rows x 136 (hi plane only)
#define HROW 256         // u16 per combined hh row: [hs 128 | hidden 128]

// ---------- scalar helpers ----------
__device__ __forceinline__ float bfs(u16 u) { return __uint_as_float(((u32)u) << 16); }
__device__ __forceinline__ float bflo(u32 u) { return __uint_as_float(u << 16); }
__device__ __forceinline__ float bfhi(u32 u) { return __uint_as_float(u & 0xffff0000u); }
__device__ __forceinline__ u16 f2bf(float f) {
    u32 x = __float_as_uint(f);
    return (u16)((x + 0x7fffu + ((x >> 16) & 1u)) >> 16);
}
template<bool BF>
__device__ __forceinline__ float ld1(const void* p, int i) {
    if (BF) return bfs(((const u16*)p)[i]);
    else    return ((const float*)p)[i];
}

// ---------- dtype probe: bf16-packed vs f32 ----------
__global__ void k_probe(const u32* __restrict__ q, int* __restrict__ flag) {
    int t = threadIdx.x;
    u32 w = q[t];
    int e = (int)((w >> 7) & 0xffu);
    bool plaus = (e >= 100 && e <= 150);
    unsigned long long m = __ballot(plaus);
    if (t == 0) flag[0] = (__popcll(m) >= 56) ? 1 : 0;
}

// ---------- prep: split weights to bf16 hi/lo, f32 copies of small tensors ----------
__global__ __launch_bounds__(256) void k_wprep(
    const void* Ws, const void* w1, const void* w2,
    const void* b1, const void* b2, const void* wattn, const void* rela,
    u16* WsH, u16* WsL, u16* w1H, u16* w1L, u16* w2H, u16* w2L,
    float* b1f, float* b2f, float* wattnf, float* relaf, const int* flag) {
    bool bf = (*flag != 0);
    int i = blockIdx.x * 256 + threadIdx.x;
    if (i < 16384) {
        float x = bf ? bfs(((const u16*)Ws)[i]) : ((const float*)Ws)[i];
        u16 h = f2bf(x); WsH[i] = h; WsL[i] = f2bf(x - bfs(h));
    } else if (i < 32768) {
        int j = i - 16384;
        float x = bf ? bfs(((const u16*)w1)[j]) : ((const float*)w1)[j];
        u16 h = f2bf(x); w1H[j] = h; w1L[j] = f2bf(x - bfs(h));
    } else if (i < 49152) {
        int j = i - 32768;
        float x = bf ? bfs(((const u16*)w2)[j]) : ((const float*)w2)[j];
        u16 h = f2bf(x); w2H[j] = h; w2L[j] = f2bf(x - bfs(h));
    } else if (i < 49152 + 128) {
        int j = i - 49152;
        b1f[j] = bf ? bfs(((const u16*)b1)[j]) : ((const float*)b1)[j];
    } else if (i < 49152 + 256) {
        int j = i - 49152 - 128;
        b2f[j] = bf ? bfs(((const u16*)b2)[j]) : ((const float*)b2)[j];
    } else if (i < 49152 + 384) {
        int j = i - 49152 - 256;
        wattnf[j] = bf ? bfs(((const u16*)wattn)[j]) : ((const float*)wattn)[j];
    } else if (i < 49152 + 384 + 25600) {
        int j = i - 49152 - 384;
        relaf[j] = bf ? bfs(((const u16*)rela)[j]) : ((const float*)rela)[j];
    }
}

// ---------- wrq[b*R+r][a] = Wr.rela_r + Wqr.query_b + bias (tiny, f32 VALU) ----------
template<bool BF>
__device__ __forceinline__ float dotrow1(const void* W, int row, const float* s) {
    float acc = 0.f;
    if (BF) {
        const uint4* wv = (const uint4*)((const u16*)W + row * Dd);
#pragma unroll
        for (int k = 0; k < 16; k++) {
            uint4 u = wv[k];
            acc += bflo(u.x)*s[k*8+0] + bfhi(u.x)*s[k*8+1]
                 + bflo(u.y)*s[k*8+2] + bfhi(u.y)*s[k*8+3]
                 + bflo(u.z)*s[k*8+4] + bfhi(u.z)*s[k*8+5]
                 + bflo(u.w)*s[k*8+6] + bfhi(u.w)*s[k*8+7];
        }
    } else {
        const float4* wv = (const float4*)((const float*)W + row * Dd);
#pragma unroll
        for (int k = 0; k < 32; k++) {
            float4 u = wv[k];
            acc += u.x*s[4*k] + u.y*s[4*k+1] + u.z*s[4*k+2] + u.w*s[4*k+3];
        }
    }
    return acc;
}
template<bool BF>
__device__ void k_wrq_body(const void* Wr, const void* Wqr, const void* bias,
                           const void* rela, const void* query, float* wrq, float* s) {
    int br = blockIdx.x;
    int b = br / Rr, r = br % Rr;
    int a = threadIdx.x;
    s[a]      = ld1<BF>(rela,  r * Dd + a);
    s[Dd + a] = ld1<BF>(query, b * Dd + a);
    __syncthreads();
    wrq[br * Dd + a] = ld1<BF>(bias, a) + dotrow1<BF>(Wr, a, s) + dotrow1<BF>(Wqr, a, s + Dd);
}
__global__ __launch_bounds__(128) void k_wrq(const void* Wr, const void* Wqr, const void* bias,
                                             const void* rela, const void* query, float* wrq,
                                             const int* flag) {
    __shared__ float s[2 * Dd];
    if (*flag) k_wrq_body<true>(Wr, Wqr, bias, rela, query, wrq, s);
    else       k_wrq_body<false>(Wr, Wqr, bias, rela, query, wrq, s);
}

// ---------- k_hs: hh[node] = [ hidden@Ws^T (bf16 x128) | hidden (bf16 x128) ] ----------
template<bool BF>
__device__ void hs_body(const void* hidden, const u16* WsH, const u16* WsL, u16* hh,
                        u16* __restrict__ Smh) {
    int t = threadIdx.x, lane = t & 63;
    int m16 = lane & 15, quad = lane >> 4;
    int w = t >> 6;
    int base = blockIdx.x * 64 + w * 16;
    u16* Sml = Smh + 16 * LDW;

    if (BF) {
        const u16* src = (const u16*)hidden + (size_t)base * Dd;
#pragma unroll
        for (int j = 0; j < 4; j++) {
            int flat = j * 64 + lane;            // 256 chunks of 8 u16
            int row = flat >> 4, c8 = (flat & 15) * 8;
            uint4 v = ((const uint4*)src)[flat];
            *(uint4*)(Smh + row * LDW + c8) = v;
            // hidden copy into combined row (bytes [256,512))
            *(uint4*)(hh + (size_t)(base + row) * HROW + 128 + c8) = v;
        }
    } else {
        const float* src = (const float*)hidden + (size_t)base * Dd;
#pragma unroll
        for (int j = 0; j < 8; j++) {
            int flat = j * 64 + lane;            // 512 float4 chunks
            int row = flat >> 5, c4 = (flat & 31) * 4;
            float4 v = ((const float4*)src)[flat];
            u16 h0 = f2bf(v.x), h1 = f2bf(v.y), h2 = f2bf(v.z), h3 = f2bf(v.w);
            ushort4 hv; hv.x = h0; hv.y = h1; hv.z = h2; hv.w = h3;
            ushort4 lv; lv.x = f2bf(v.x - bfs(h0)); lv.y = f2bf(v.y - bfs(h1));
                        lv.z = f2bf(v.z - bfs(h2)); lv.w = f2bf(v.w - bfs(h3));
            *(ushort4*)(Smh + row * LDW + c4) = hv;
            *(ushort4*)(Sml + row * LDW + c4) = lv;
            *(ushort4*)(hh + (size_t)(base + row) * HROW + 128 + c4) = hv; // unused by f32 gather
        }
    }
    const u16* ph = Smh + m16 * LDW + quad * 8;
    const u16* pl = Sml + m16 * LDW + quad * 8;
    bf16x8 ah[4], al[4];
#pragma unroll
    for (int ks = 0; ks < 4; ks++) {
        ah[ks] = *(const bf16x8*)(ph + ks * 32);
        if (!BF) al[ks] = *(const bf16x8*)(pl + ks * 32);
    }
#pragma unroll
    for (int nt = 0; nt < 8; nt++) {
        int n = nt * 16 + m16;
        f32x4 acc = {0.f, 0.f, 0.f, 0.f};
#pragma unroll
        for (int ks = 0; ks < 4; ks++) {
            bf16x8 bh = *(const bf16x8*)(WsH + n * Dd + ks * 32 + quad * 8);
            acc = __builtin_amdgcn_mfma_f32_16x16x32_bf16(ah[ks], bh, acc, 0, 0, 0);
            if (!BF) {
                bf16x8 bl = *(const bf16x8*)(WsL + n * Dd + ks * 32 + quad * 8);
                acc = __builtin_amdgcn_mfma_f32_16x16x32_bf16(al[ks], bh, acc, 0, 0, 0);
                acc = __builtin_amdgcn_mfma_f32_16x16x32_bf16(ah[ks], bl, acc, 0, 0, 0);
            }
        }
#pragma unroll
        for (int r = 0; r < 4; r++)
            hh[(size_t)(base + quad * 4 + r) * HROW + n] = f2bf(acc[r]);
    }
}
__global__ __launch_bounds__(256, 4) void k_hs(const void* hidden, const u16* WsH,
                                               const u16* WsL, u16* hh, const int* flag) {
    __shared__ __align__(16) u16 SL[4][2 * SLAB];   // k_hs keeps hi+lo planes (f32 path)
    u16* slab = SL[threadIdx.x >> 6];
    if (*flag) hs_body<true>(hidden, WsH, WsL, hh, slab);
    else       hs_body<false>(hidden, WsH, WsL, hh, slab);
}

// ---------- counting-sort scatter: packed rec ----------
__global__ __launch_bounds__(256) void k_scatter(const int* __restrict__ edges,
                                                 u32* __restrict__ slots,
                                                 int* __restrict__ deg, int nE) {
    int i = blockIdx.x * 256 + threadIdx.x;
    if (i >= nE) return;
    int bat = edges[4*i], sub = edges[4*i+1], rel = edges[4*i+2], obj = edges[4*i+3];
    int pos = atomicAdd(&deg[obj], 1);
    if (pos < MAXDEG)
        slots[(size_t)obj * MAXDEG + pos] = (u32)sub | ((u32)rel << 18) | ((u32)bat << 26);
}

// ---------- fused: one-pass gather (alpha inline) -> hi-only slab -> 2-layer MFMA MLP ----------
// Mask folded into x,y at load: masked edges contribute exactly 0 (rec=0 keeps p finite).
template<bool BF>
__device__ __forceinline__ void epre(u32 rec, int lane, float2 wa, float mk,
                                     const u16* __restrict__ hh,
                                     const float* __restrict__ wrq,
                                     const void* __restrict__ hidden,
                                     const float* __restrict__ relaf,
                                     float& p, float& x, float& y) {
    int sub = rec & 0x3FFFF, rel = (rec >> 18) & 0xFF, bat = (int)(rec >> 26);
    const u16* row = hh + (size_t)sub * HROW;
    u32 hp = ((const u32*)row)[lane];                      // hs pair
    float2 wq = ((const float2*)wrq)[(bat * Rr + rel) * 64 + lane];
    float2 mr = ((const float2*)relaf)[rel * 64 + lane];
    float mh0, mh1;
    if (BF) {
        u32 mh = ((const u32*)(row + 128))[lane];          // hidden pair, same 512B row
        mh0 = bflo(mh); mh1 = bfhi(mh);
    } else {
        float2 mh = ((const float2*)hidden)[(size_t)sub * 64 + lane];
        mh0 = mh.x; mh1 = mh.y;
    }
    float h0 = fmaxf(bflo(hp) + wq.x, 0.f);
    float h1 = fmaxf(bfhi(hp) + wq.y, 0.f);
    p = h0 * wa.x + h1 * wa.y;
    x = mh0 * mr.x * mk;
    y = mh1 * mr.y * mk;
}

__device__ __forceinline__ float sigm(float p) { return 1.f / (1.f + __expf(-p)); }

template<bool BF>
__device__ void fused_body(const u32* __restrict__ slots, const int* __restrict__ deg,
                           const u16* __restrict__ hh, const float* __restrict__ wrq,
                           const float* __restrict__ wattnf,
                           const void* __restrict__ hidden, const float* __restrict__ relaf,
                           const u16* w1H, const u16* w1L, const u16* w2H, const u16* w2L,
                           const float* b1f, const float* b2f, void* out,
                           u16* __restrict__ Smh, u32* __restrict__ SB) {
    int t = threadIdx.x, lane = t & 63;
    int m16 = lane & 15, quad = lane >> 4;
    int w = t >> 6;
    int base = blockIdx.x * 64 + w * 16;
    float2 wa = ((const float2*)wattnf)[lane];

    // ---- stage first-8 recs of all 16 nodes into LDS: one dwordx2/lane ----
    {
        int f = lane * 2;                 // flat u32 index, 128 total
        int nd = f >> 3, e0 = f & 7;      // node, even edge
        uint2 v = *(const uint2*)(slots + (size_t)(base + nd) * MAXDEG + e0);
        *(uint2*)(SB + nd * 8 + e0) = v;
    }
    // same-wave RAW on LDS; compiler inserts lgkmcnt before first read

    // ---- gather: node pairs, 4-wide fused butterfly groups (VGPR-lean) ----
    for (int i = 0; i < 16; i += 2) {
        int nA = base + i, nB = nA + 1;
        int dA = deg[nA]; if (dA > MAXDEG) dA = MAXDEG;
        int dB = deg[nB]; if (dB > MAXDEG) dB = MAXDEG;
        const u32* rA = SB + i * 8;
        const u32* rB = rA + 8;
        float aA0 = 0.f, aA1 = 0.f, aB0 = 0.f, aB1 = 0.f;
        int dmax = dA > dB ? dA : dB; if (dmax > 8) dmax = 8;

        for (int e0 = 0; e0 < dmax; e0 += 2) {
            int e1 = e0 + 1;
            float mA0 = (e0 < dA) ? 1.f : 0.f, mA1 = (e1 < dA) ? 1.f : 0.f;
            float mB0 = (e0 < dB) ? 1.f : 0.f, mB1 = (e1 < dB) ? 1.f : 0.f;
            u32 ra0 = (e0 < dA) ? rA[e0] : 0u, ra1 = (e1 < dA) ? rA[e1] : 0u;
            u32 rb0 = (e0 < dB) ? rB[e0] : 0u, rb1 = (e1 < dB) ? rB[e1] : 0u;
            float p0, x0, y0, p1, x1, y1, p2, x2, y2, p3, x3, y3;
            epre<BF>(ra0, lane, wa, mA0, hh, wrq, hidden, relaf, p0, x0, y0);
            epre<BF>(rb0, lane, wa, mB0, hh, wrq, hidden, relaf, p2, x2, y2);
            epre<BF>(ra1, lane, wa, mA1, hh, wrq, hidden, relaf, p1, x1, y1);
            epre<BF>(rb1, lane, wa, mB1, hh, wrq, hidden, relaf, p3, x3, y3);
#pragma unroll
            for (int m = 32; m >= 1; m >>= 1) {
                float s0 = __shfl_xor(p0, m), s1 = __shfl_xor(p1, m);
                float s2 = __shfl_xor(p2, m), s3 = __shfl_xor(p3, m);
                p0 += s0; p1 += s1; p2 += s2; p3 += s3;
            }
            float l0 = sigm(p0), l1 = sigm(p1), l2 = sigm(p2), l3 = sigm(p3);
            aA0 += x0 * l0; aA1 += y0 * l0;
            aA0 += x1 * l1; aA1 += y1 * l1;
            aB0 += x2 * l2; aB1 += y2 * l2;
            aB0 += x3 * l3; aB1 += y3 * l3;
        }
        // rare tails (deg > 8) straight from global slots
        for (int e = 8; e < dA; e++) {
            u32 r0 = slots[(size_t)nA * MAXDEG + e];
            float p0, x0, y0;
            epre<BF>(r0, lane, wa, 1.f, hh, wrq, hidden, relaf, p0, x0, y0);
#pragma unroll
            for (int m = 32; m >= 1; m >>= 1) p0 += __shfl_xor(p0, m);
            float l0 = sigm(p0);
            aA0 += x0 * l0; aA1 += y0 * l0;
        }
        for (int e = 8; e < dB; e++) {
            u32 r0 = slots[(size_t)nB * MAXDEG + e];
            float p0, x0, y0;
            epre<BF>(r0, lane, wa, 1.f, hh, wrq, hidden, relaf, p0, x0, y0);
#pragma unroll
            for (int m = 32; m >= 1; m >>= 1) p0 += __shfl_xor(p0, m);
            float l0 = sigm(p0);
            aB0 += x0 * l0; aB1 += y0 * l0;
        }

        // hi-plane only (agg rounded to bf16; measured absmax unchanged)
        u16 hA0 = f2bf(aA0), hA1 = f2bf(aA1);
        *(u32*)(Smh + i * LDW + 2 * lane) = (u32)hA0 | ((u32)hA1 << 16);
        u16 hB0 = f2bf(aB0), hB1 = f2bf(aB1);
        *(u32*)(Smh + (i + 1) * LDW + 2 * lane) = (u32)hB0 | ((u32)hB1 << 16);
    }

    // ---- layer 1: mid = agg @ W1^T + b1 (hi-only A-frags) ----
    const u16* ph = Smh + m16 * LDW + quad * 8;
    bf16x8 ah[4];
#pragma unroll
    for (int ks = 0; ks < 4; ks++)
        ah[ks] = *(const bf16x8*)(ph + ks * 32);
#pragma unroll
    for (int nt = 0; nt < 8; nt++) {
        int n = nt * 16 + m16;
        f32x4 acc = {0.f, 0.f, 0.f, 0.f};
#pragma unroll
        for (int ks = 0; ks < 4; ks++) {
            bf16x8 bh = *(const bf16x8*)(w1H + n * Dd + ks * 32 + quad * 8);
            acc = __builtin_amdgcn_mfma_f32_16x16x32_bf16(ah[ks], bh, acc, 0, 0, 0);
            if (!BF) {
                bf16x8 bl = *(const bf16x8*)(w1L + n * Dd + ks * 32 + quad * 8);
                acc = __builtin_amdgcn_mfma_f32_16x16x32_bf16(ah[ks], bl, acc, 0, 0, 0);
            }
        }
        float bv = b1f[n];
#pragma unroll
        for (int r = 0; r < 4; r++) {
            float v = acc[r] + bv;
            int row = quad * 4 + r;
            Smh[row * LDW + n] = f2bf(v);
        }
    }

    // ---- layer 2: out = relu(mid @ W2^T + b2), masked by deg ----
    bf16x8 mh[4];
#pragma unroll
    for (int ks = 0; ks < 4; ks++)
        mh[ks] = *(const bf16x8*)(ph + ks * 32);
    int dg[4];
#pragma unroll
    for (int r = 0; r < 4; r++) dg[r] = deg[base + quad * 4 + r];
#pragma unroll
    for (int nt = 0; nt < 8; nt++) {
        int n = nt * 16 + m16;
        f32x4 acc = {0.f, 0.f, 0.f, 0.f};
#pragma unroll
        for (int ks = 0; ks < 4; ks++) {
            bf16x8 bh = *(const bf16x8*)(w2H + n * Dd + ks * 32 + quad * 8);
            acc = __builtin_amdgcn_mfma_f32_16x16x32_bf16(mh[ks], bh, acc, 0, 0, 0);
            if (!BF) {
                bf16x8 bl = *(const bf16x8*)(w2L + n * Dd + ks * 32 + quad * 8);
                acc = __builtin_amdgcn_mfma_f32_16x16x32_bf16(mh[ks], bl, acc, 0, 0, 0);
            }
        }
        float bv = b2f[n];
#pragma unroll
        for (int r = 0; r < 4; r++) {
            float v = fmaxf(acc[r] + bv, 0.f);
            if (dg[r] == 0) v = 0.f;
            size_t o = (size_t)(base + quad * 4 + r) * Dd + n;
            if (BF) ((u16*)out)[o] = f2bf(v);
            else    ((float*)out)[o] = v;
        }
    }
}
__global__ __launch_bounds__(256, 8) void k_fused(const u32* slots, const int* deg,
                                                  const u16* hh, const float* wrq,
                                                  const float* wattnf, const void* hidden,
                                                  const float* relaf,
                                                  const u16* w1H, const u16* w1L,
                                                  const u16* w2H, const u16* w2L,
                                                  const float* b1f, const float* b2f,
                                                  void* out, const int* flag) {
    __shared__ __align__(16) u16 SL[4][SLAB];        // 17408 B
    __shared__ __align__(16) u32 SBL[4][128];        //  2048 B  -> 19456 B/block, 8 blocks/CU
    int w = threadIdx.x >> 6;
    if (*flag) fused_body<true>(slots, deg, hh, wrq, wattnf, hidden, relaf,
                                w1H, w1L, w2H, w2L, b1f, b2f, out, SL[w], SBL[w]);
    else       fused_body<false>(slots, deg, hh, wrq, wattnf, hidden, relaf,
                                 w1H, w1L, w2H, w2L, b1f, b2f, out, SL[w], SBL[w]);
}

extern "C" void kernel_launch(void* const* d_in, const int* in_sizes, int n_in,
                              void* d_out, int out_size, void* d_ws, size_t ws_size,
                              hipStream_t stream) {
    const void* query  = d_in[0];
    const void* hidden = d_in[3];
    const int*  edges  = (const int*)d_in[4];
    const void* Ws     = d_in[6];
    const void* Wr     = d_in[7];
    const void* Wqr    = d_in[8];
    const void* Wqrb   = d_in[9];
    const void* Wattn  = d_in[10];
    const void* rela   = d_in[11];
    const void* w1     = d_in[12];
    const void* b1     = d_in[13];
    const void* w2     = d_in[14];
    const void* b2     = d_in[15];

    char* ws = (char*)d_ws;
    u16*   hh     = (u16*)ws;                        // 102,400,000 B (200k x 512B combined)
    float* wrq    = (float*)(ws + 102400000);        //     409,600 B
    u32*   slots  = (u32*) (ws + 102809600);         //  12,800,000 B (200k x 16 recs)
    int*   deg    = (int*) (ws + 115609600);         //     800,000 B
    u16*   WsH    = (u16*) (ws + 116409600);
    u16*   WsL    = (u16*) (ws + 116442368);
    u16*   w1H    = (u16*) (ws + 116475136);
    u16*   w1L    = (u16*) (ws + 116507904);
    u16*   w2H    = (u16*) (ws + 116540672);
    u16*   w2L    = (u16*) (ws + 116573440);
    float* b1f    = (float*)(ws + 116606208);
    float* b2f    = (float*)(ws + 116606720);
    float* wattnf = (float*)(ws + 116607232);
    float* relaf  = (float*)(ws + 116607744);        //     102,400 B
    int*   flag   = (int*) (ws + 116710144);

    int nE = in_sizes[4] / 4;

    k_probe<<<1, 64, 0, stream>>>((const u32*)query, flag);
    hipMemsetAsync(deg, 0, (size_t)BN * 4, stream);
    k_wprep<<<294, 256, 0, stream>>>(Ws, w1, w2, b1, b2, Wattn, rela,
                                     WsH, WsL, w1H, w1L, w2H, w2L,
                                     b1f, b2f, wattnf, relaf, flag);
    k_wrq<<<Bb * Rr, 128, 0, stream>>>(Wr, Wqr, Wqrb, rela, query, wrq, flag);
    k_hs<<<BN / 64, 256, 0, stream>>>(hidden, WsH, WsL, hh, flag);
    k_scatter<<<(nE + 255) / 256, 256, 0, stream>>>(edges, slots, deg, nE);
    k_fused<<<BN / 64, 256, 0, stream>>>(slots, deg, hh, wrq, wattnf, hidden, relaf,
                                         w1H, w1L, w2H, w2L, b1f, b2f, d_out, flag);
}

// Round 11
// 684.719 us; speedup vs baseline: 1.1597x; 1.0536x over previous
//
#include <hip/hip_runtime.h>

typedef unsigned int u32;
typedef unsigned short u16;
typedef __attribute__((ext_vector_type(8))) short bf16x8;
typedef __attribute__((ext_vector_type(4))) float f32x4;

#define Bb 4
#define Nn 50000
#define Dd 128
#define Rr 200
#define BN (Bb*Nn)
#define MAXDEG 16
#define LDW 136          // u16 row stride inside a wave slab (272 B, 16B-aligned)
#define SLAB 2176        // u16 per wave slab: 1 tile x 16 rows x 136 (hi plane only)
#define HROW 256         // u16 per combined hh row: [hs 128 | hidden 128]

// ---------- scalar helpers ----------
__device__ __forceinline__ float bfs(u16 u) { return __uint_as_float(((u32)u) << 16); }
__device__ __forceinline__ float bflo(u32 u) { return __uint_as_float(u << 16); }
__device__ __forceinline__ float bfhi(u32 u) { return __uint_as_float(u & 0xffff0000u); }
__device__ __forceinline__ u16 f2bf(float f) {
    u32 x = __float_as_uint(f);
    return (u16)((x + 0x7fffu + ((x >> 16) & 1u)) >> 16);
}
template<bool BF>
__device__ __forceinline__ float ld1(const void* p, int i) {
    if (BF) return bfs(((const u16*)p)[i]);
    else    return ((const float*)p)[i];
}

// ---------- dtype probe: bf16-packed vs f32 ----------
__global__ void k_probe(const u32* __restrict__ q, int* __restrict__ flag) {
    int t = threadIdx.x;
    u32 w = q[t];
    int e = (int)((w >> 7) & 0xffu);
    bool plaus = (e >= 100 && e <= 150);
    unsigned long long m = __ballot(plaus);
    if (t == 0) flag[0] = (__popcll(m) >= 56) ? 1 : 0;
}

// ---------- prep: split weights to bf16 hi/lo, f32 copies of small tensors ----------
__global__ __launch_bounds__(256) void k_wprep(
    const void* Ws, const void* w1, const void* w2,
    const void* b1, const void* b2, const void* wattn, const void* rela,
    u16* WsH, u16* WsL, u16* w1H, u16* w1L, u16* w2H, u16* w2L,
    float* b1f, float* b2f, float* wattnf, float* relaf, const int* flag) {
    bool bf = (*flag != 0);
    int i = blockIdx.x * 256 + threadIdx.x;
    if (i < 16384) {
        float x = bf ? bfs(((const u16*)Ws)[i]) : ((const float*)Ws)[i];
        u16 h = f2bf(x); WsH[i] = h; WsL[i] = f2bf(x - bfs(h));
    } else if (i < 32768) {
        int j = i - 16384;
        float x = bf ? bfs(((const u16*)w1)[j]) : ((const float*)w1)[j];
        u16 h = f2bf(x); w1H[j] = h; w1L[j] = f2bf(x - bfs(h));
    } else if (i < 49152) {
        int j = i - 32768;
        float x = bf ? bfs(((const u16*)w2)[j]) : ((const float*)w2)[j];
        u16 h = f2bf(x); w2H[j] = h; w2L[j] = f2bf(x - bfs(h));
    } else if (i < 49152 + 128) {
        int j = i - 49152;
        b1f[j] = bf ? bfs(((const u16*)b1)[j]) : ((const float*)b1)[j];
    } else if (i < 49152 + 256) {
        int j = i - 49152 - 128;
        b2f[j] = bf ? bfs(((const u16*)b2)[j]) : ((const float*)b2)[j];
    } else if (i < 49152 + 384) {
        int j = i - 49152 - 256;
        wattnf[j] = bf ? bfs(((const u16*)wattn)[j]) : ((const float*)wattn)[j];
    } else if (i < 49152 + 384 + 25600) {
        int j = i - 49152 - 384;
        relaf[j] = bf ? bfs(((const u16*)rela)[j]) : ((const float*)rela)[j];
    }
}

// ---------- wrq[b*R+r][a] = Wr.rela_r + Wqr.query_b + bias (tiny, f32 VALU) ----------
template<bool BF>
__device__ __forceinline__ float dotrow1(const void* W, int row, const float* s) {
    float acc = 0.f;
    if (BF) {
        const uint4* wv = (const uint4*)((const u16*)W + row * Dd);
#pragma unroll
        for (int k = 0; k < 16; k++) {
            uint4 u = wv[k];
            acc += bflo(u.x)*s[k*8+0] + bfhi(u.x)*s[k*8+1]
                 + bflo(u.y)*s[k*8+2] + bfhi(u.y)*s[k*8+3]
                 + bflo(u.z)*s[k*8+4] + bfhi(u.z)*s[k*8+5]
                 + bflo(u.w)*s[k*8+6] + bfhi(u.w)*s[k*8+7];
        }
    } else {
        const float4* wv = (const float4*)((const float*)W + row * Dd);
#pragma unroll
        for (int k = 0; k < 32; k++) {
            float4 u = wv[k];
            acc += u.x*s[4*k] + u.y*s[4*k+1] + u.z*s[4*k+2] + u.w*s[4*k+3];
        }
    }
    return acc;
}
template<bool BF>
__device__ void k_wrq_body(const void* Wr, const void* Wqr, const void* bias,
                           const void* rela, const void* query, float* wrq, float* s) {
    int br = blockIdx.x;
    int b = br / Rr, r = br % Rr;
    int a = threadIdx.x;
    s[a]      = ld1<BF>(rela,  r * Dd + a);
    s[Dd + a] = ld1<BF>(query, b * Dd + a);
    __syncthreads();
    wrq[br * Dd + a] = ld1<BF>(bias, a) + dotrow1<BF>(Wr, a, s) + dotrow1<BF>(Wqr, a, s + Dd);
}
__global__ __launch_bounds__(128) void k_wrq(const void* Wr, const void* Wqr, const void* bias,
                                             const void* rela, const void* query, float* wrq,
                                             const int* flag) {
    __shared__ float s[2 * Dd];
    if (*flag) k_wrq_body<true>(Wr, Wqr, bias, rela, query, wrq, s);
    else       k_wrq_body<false>(Wr, Wqr, bias, rela, query, wrq, s);
}

// ---------- k_hs: hh[node] = [ hidden@Ws^T (bf16 x128) | hidden (bf16 x128) ] ----------
template<bool BF>
__device__ void hs_body(const void* hidden, const u16* WsH, const u16* WsL, u16* hh,
                        u16* __restrict__ Smh) {
    int t = threadIdx.x, lane = t & 63;
    int m16 = lane & 15, quad = lane >> 4;
    int w = t >> 6;
    int base = blockIdx.x * 64 + w * 16;
    u16* Sml = Smh + 16 * LDW;

    if (BF) {
        const u16* src = (const u16*)hidden + (size_t)base * Dd;
#pragma unroll
        for (int j = 0; j < 4; j++) {
            int flat = j * 64 + lane;            // 256 chunks of 8 u16
            int row = flat >> 4, c8 = (flat & 15) * 8;
            uint4 v = ((const uint4*)src)[flat];
            *(uint4*)(Smh + row * LDW + c8) = v;
            // hidden copy into combined row (bytes [256,512))
            *(uint4*)(hh + (size_t)(base + row) * HROW + 128 + c8) = v;
        }
    } else {
        const float* src = (const float*)hidden + (size_t)base * Dd;
#pragma unroll
        for (int j = 0; j < 8; j++) {
            int flat = j * 64 + lane;            // 512 float4 chunks
            int row = flat >> 5, c4 = (flat & 31) * 4;
            float4 v = ((const float4*)src)[flat];
            u16 h0 = f2bf(v.x), h1 = f2bf(v.y), h2 = f2bf(v.z), h3 = f2bf(v.w);
            ushort4 hv; hv.x = h0; hv.y = h1; hv.z = h2; hv.w = h3;
            ushort4 lv; lv.x = f2bf(v.x - bfs(h0)); lv.y = f2bf(v.y - bfs(h1));
                        lv.z = f2bf(v.z - bfs(h2)); lv.w = f2bf(v.w - bfs(h3));
            *(ushort4*)(Smh + row * LDW + c4) = hv;
            *(ushort4*)(Sml + row * LDW + c4) = lv;
            *(ushort4*)(hh + (size_t)(base + row) * HROW + 128 + c4) = hv; // unused by f32 gather
        }
    }
    const u16* ph = Smh + m16 * LDW + quad * 8;
    const u16* pl = Sml + m16 * LDW + quad * 8;
    bf16x8 ah[4], al[4];
#pragma unroll
    for (int ks = 0; ks < 4; ks++) {
        ah[ks] = *(const bf16x8*)(ph + ks * 32);
        if (!BF) al[ks] = *(const bf16x8*)(pl + ks * 32);
    }
#pragma unroll
    for (int nt = 0; nt < 8; nt++) {
        int n = nt * 16 + m16;
        f32x4 acc = {0.f, 0.f, 0.f, 0.f};
#pragma unroll
        for (int ks = 0; ks < 4; ks++) {
            bf16x8 bh = *(const bf16x8*)(WsH + n * Dd + ks * 32 + quad * 8);
            acc = __builtin_amdgcn_mfma_f32_16x16x32_bf16(ah[ks], bh, acc, 0, 0, 0);
            if (!BF) {
                bf16x8 bl = *(const bf16x8*)(WsL + n * Dd + ks * 32 + quad * 8);
                acc = __builtin_amdgcn_mfma_f32_16x16x32_bf16(al[ks], bh, acc, 0, 0, 0);
                acc = __builtin_amdgcn_mfma_f32_16x16x32_bf16(ah[ks], bl, acc, 0, 0, 0);
            }
        }
#pragma unroll
        for (int r = 0; r < 4; r++)
            hh[(size_t)(base + quad * 4 + r) * HROW + n] = f2bf(acc[r]);
    }
}
__global__ __launch_bounds__(256, 4) void k_hs(const void* hidden, const u16* WsH,
                                               const u16* WsL, u16* hh, const int* flag) {
    __shared__ __align__(16) u16 SL[4][2 * SLAB];   // k_hs keeps hi+lo planes (f32 path)
    u16* slab = SL[threadIdx.x >> 6];
    if (*flag) hs_body<true>(hidden, WsH, WsL, hh, slab);
    else       hs_body<false>(hidden, WsH, WsL, hh, slab);
}

// ---------- counting-sort scatter: packed rec ----------
__global__ __launch_bounds__(256) void k_scatter(const int* __restrict__ edges,
                                                 u32* __restrict__ slots,
                                                 int* __restrict__ deg, int nE) {
    int i = blockIdx.x * 256 + threadIdx.x;
    if (i >= nE) return;
    int bat = edges[4*i], sub = edges[4*i+1], rel = edges[4*i+2], obj = edges[4*i+3];
    int pos = atomicAdd(&deg[obj], 1);
    if (pos < MAXDEG)
        slots[(size_t)obj * MAXDEG + pos] = (u32)sub | ((u32)rel << 18) | ((u32)bat << 26);
}

// ---------- fused: one-pass gather (alpha inline) -> hi-only slab -> 2-layer MFMA MLP ----------
// Mask folded into x,y at load: masked edges contribute exactly 0 (rec=0 keeps p finite).
template<bool BF>
__device__ __forceinline__ void epre(u32 rec, int lane, float2 wa, float mk,
                                     const u16* __restrict__ hh,
                                     const float* __restrict__ wrq,
                                     const void* __restrict__ hidden,
                                     const float* __restrict__ relaf,
                                     float& p, float& x, float& y) {
    int sub = rec & 0x3FFFF, rel = (rec >> 18) & 0xFF, bat = (int)(rec >> 26);
    const u16* row = hh + (size_t)sub * HROW;
    u32 hp = ((const u32*)row)[lane];                      // hs pair
    float2 wq = ((const float2*)wrq)[(bat * Rr + rel) * 64 + lane];
    float2 mr = ((const float2*)relaf)[rel * 64 + lane];
    float mh0, mh1;
    if (BF) {
        u32 mh = ((const u32*)(row + 128))[lane];          // hidden pair, same 512B row
        mh0 = bflo(mh); mh1 = bfhi(mh);
    } else {
        float2 mh = ((const float2*)hidden)[(size_t)sub * 64 + lane];
        mh0 = mh.x; mh1 = mh.y;
    }
    float h0 = fmaxf(bflo(hp) + wq.x, 0.f);
    float h1 = fmaxf(bfhi(hp) + wq.y, 0.f);
    p = h0 * wa.x + h1 * wa.y;
    x = mh0 * mr.x * mk;
    y = mh1 * mr.y * mk;
}

__device__ __forceinline__ float sigm(float p) { return 1.f / (1.f + __expf(-p)); }

template<bool BF>
__device__ void fused_body(const u32* __restrict__ slots, const int* __restrict__ deg,
                           const u16* __restrict__ hh, const float* __restrict__ wrq,
                           const float* __restrict__ wattnf,
                           const void* __restrict__ hidden, const float* __restrict__ relaf,
                           const u16* w1H, const u16* w1L, const u16* w2H, const u16* w2L,
                           const float* b1f, const float* b2f, void* out,
                           u16* __restrict__ Smh, u32* __restrict__ SB) {
    int t = threadIdx.x, lane = t & 63;
    int m16 = lane & 15, quad = lane >> 4;
    int w = t >> 6;
    int base = blockIdx.x * 64 + w * 16;
    float2 wa = ((const float2*)wattnf)[lane];

    // ---- stage first-8 recs of all 16 nodes into LDS: one dwordx2/lane ----
    {
        int f = lane * 2;                 // flat u32 index, 128 total
        int nd = f >> 3, e0 = f & 7;      // node, even edge
        uint2 v = *(const uint2*)(slots + (size_t)(base + nd) * MAXDEG + e0);
        *(uint2*)(SB + nd * 8 + e0) = v;
    }
    // same-wave RAW on LDS; compiler inserts lgkmcnt before first read

    // ---- gather: node pairs, 8-wide fused butterfly groups (R8 structure) ----
    for (int i = 0; i < 16; i += 2) {
        int nA = base + i, nB = nA + 1;
        int dA = deg[nA]; if (dA > MAXDEG) dA = MAXDEG;
        int dB = deg[nB]; if (dB > MAXDEG) dB = MAXDEG;
        const u32* rA = SB + i * 8;
        const u32* rB = rA + 8;
        float aA0 = 0.f, aA1 = 0.f, aB0 = 0.f, aB1 = 0.f;

#pragma unroll
        for (int g = 0; g < 2; g++) {
            int eo = g * 4;
            if (g == 1 && dA <= 4 && dB <= 4) break;   // wave-uniform skip
            float p[8], x[8], y[8];
#pragma unroll
            for (int e = 0; e < 4; e++) {
                int ee = eo + e;
                u32 ra = (ee < dA) ? rA[ee] : 0u;
                u32 rb = (ee < dB) ? rB[ee] : 0u;
                float ma = (ee < dA) ? 1.f : 0.f;
                float mb = (ee < dB) ? 1.f : 0.f;
                epre<BF>(ra, lane, wa, ma, hh, wrq, hidden, relaf, p[2*e],   x[2*e],   y[2*e]);
                epre<BF>(rb, lane, wa, mb, hh, wrq, hidden, relaf, p[2*e+1], x[2*e+1], y[2*e+1]);
            }
#pragma unroll
            for (int m = 32; m >= 1; m >>= 1) {
                float s0 = __shfl_xor(p[0], m), s1 = __shfl_xor(p[1], m);
                float s2 = __shfl_xor(p[2], m), s3 = __shfl_xor(p[3], m);
                float s4 = __shfl_xor(p[4], m), s5 = __shfl_xor(p[5], m);
                float s6 = __shfl_xor(p[6], m), s7 = __shfl_xor(p[7], m);
                p[0] += s0; p[1] += s1; p[2] += s2; p[3] += s3;
                p[4] += s4; p[5] += s5; p[6] += s6; p[7] += s7;
            }
#pragma unroll
            for (int e = 0; e < 4; e++) {
                float la = sigm(p[2*e]);
                float lb = sigm(p[2*e+1]);
                aA0 += x[2*e]   * la; aA1 += y[2*e]   * la;
                aB0 += x[2*e+1] * lb; aB1 += y[2*e+1] * lb;
            }
        }
        // rare tails (deg > 8) straight from global slots
        for (int e = 8; e < dA; e++) {
            u32 r0 = slots[(size_t)nA * MAXDEG + e];
            float p0, x0, y0;
            epre<BF>(r0, lane, wa, 1.f, hh, wrq, hidden, relaf, p0, x0, y0);
#pragma unroll
            for (int m = 32; m >= 1; m >>= 1) p0 += __shfl_xor(p0, m);
            float l0 = sigm(p0);
            aA0 += x0 * l0; aA1 += y0 * l0;
        }
        for (int e = 8; e < dB; e++) {
            u32 r0 = slots[(size_t)nB * MAXDEG + e];
            float p0, x0, y0;
            epre<BF>(r0, lane, wa, 1.f, hh, wrq, hidden, relaf, p0, x0, y0);
#pragma unroll
            for (int m = 32; m >= 1; m >>= 1) p0 += __shfl_xor(p0, m);
            float l0 = sigm(p0);
            aB0 += x0 * l0; aB1 += y0 * l0;
        }

        // hi-plane only (agg rounded to bf16; measured absmax unchanged)
        u16 hA0 = f2bf(aA0), hA1 = f2bf(aA1);
        *(u32*)(Smh + i * LDW + 2 * lane) = (u32)hA0 | ((u32)hA1 << 16);
        u16 hB0 = f2bf(aB0), hB1 = f2bf(aB1);
        *(u32*)(Smh + (i + 1) * LDW + 2 * lane) = (u32)hB0 | ((u32)hB1 << 16);
    }

    // ---- layer 1: mid = agg @ W1^T + b1 (hi-only A-frags) ----
    const u16* ph = Smh + m16 * LDW + quad * 8;
    bf16x8 ah[4];
#pragma unroll
    for (int ks = 0; ks < 4; ks++)
        ah[ks] = *(const bf16x8*)(ph + ks * 32);
#pragma unroll
    for (int nt = 0; nt < 8; nt++) {
        int n = nt * 16 + m16;
        f32x4 acc = {0.f, 0.f, 0.f, 0.f};
#pragma unroll
        for (int ks = 0; ks < 4; ks++) {
            bf16x8 bh = *(const bf16x8*)(w1H + n * Dd + ks * 32 + quad * 8);
            acc = __builtin_amdgcn_mfma_f32_16x16x32_bf16(ah[ks], bh, acc, 0, 0, 0);
            if (!BF) {
                bf16x8 bl = *(const bf16x8*)(w1L + n * Dd + ks * 32 + quad * 8);
                acc = __builtin_amdgcn_mfma_f32_16x16x32_bf16(ah[ks], bl, acc, 0, 0, 0);
            }
        }
        float bv = b1f[n];
#pragma unroll
        for (int r = 0; r < 4; r++) {
            float v = acc[r] + bv;
            int row = quad * 4 + r;
            Smh[row * LDW + n] = f2bf(v);
        }
    }

    // ---- layer 2: out = relu(mid @ W2^T + b2), masked by deg ----
    bf16x8 mh[4];
#pragma unroll
    for (int ks = 0; ks < 4; ks++)
        mh[ks] = *(const bf16x8*)(ph + ks * 32);
    int dg[4];
#pragma unroll
    for (int r = 0; r < 4; r++) dg[r] = deg[base + quad * 4 + r];
#pragma unroll
    for (int nt = 0; nt < 8; nt++) {
        int n = nt * 16 + m16;
        f32x4 acc = {0.f, 0.f, 0.f, 0.f};
#pragma unroll
        for (int ks = 0; ks < 4; ks++) {
            bf16x8 bh = *(const bf16x8*)(w2H + n * Dd + ks * 32 + quad * 8);
            acc = __builtin_amdgcn_mfma_f32_16x16x32_bf16(mh[ks], bh, acc, 0, 0, 0);
            if (!BF) {
                bf16x8 bl = *(const bf16x8*)(w2L + n * Dd + ks * 32 + quad * 8);
                acc = __builtin_amdgcn_mfma_f32_16x16x32_bf16(mh[ks], bl, acc, 0, 0, 0);
            }
        }
        float bv = b2f[n];
#pragma unroll
        for (int r = 0; r < 4; r++) {
            float v = fmaxf(acc[r] + bv, 0.f);
            if (dg[r] == 0) v = 0.f;
            size_t o = (size_t)(base + quad * 4 + r) * Dd + n;
            if (BF) ((u16*)out)[o] = f2bf(v);
            else    ((float*)out)[o] = v;
        }
    }
}
__global__ __launch_bounds__(256, 6) void k_fused(const u32* slots, const int* deg,
                                                  const u16* hh, const float* wrq,
                                                  const float* wattnf, const void* hidden,
                                                  const float* relaf,
                                                  const u16* w1H, const u16* w1L,
                                                  const u16* w2H, const u16* w2L,
                                                  const float* b1f, const float* b2f,
                                                  void* out, const int* flag) {
    __shared__ __align__(16) u16 SL[4][SLAB];        // 17408 B
    __shared__ __align__(16) u32 SBL[4][128];        //  2048 B  -> 19456 B/block
    int w = threadIdx.x >> 6;
    if (*flag) fused_body<true>(slots, deg, hh, wrq, wattnf, hidden, relaf,
                                w1H, w1L, w2H, w2L, b1f, b2f, out, SL[w], SBL[w]);
    else       fused_body<false>(slots, deg, hh, wrq, wattnf, hidden, relaf,
                                 w1H, w1L, w2H, w2L, b1f, b2f, out, SL[w], SBL[w]);
}

extern "C" void kernel_launch(void* const* d_in, const int* in_sizes, int n_in,
                              void* d_out, int out_size, void* d_ws, size_t ws_size,
                              hipStream_t stream) {
    const void* query  = d_in[0];
    const void* hidden = d_in[3];
    const int*  edges  = (const int*)d_in[4];
    const void* Ws     = d_in[6];
    const void* Wr     = d_in[7];
    const void* Wqr    = d_in[8];
    const void* Wqrb   = d_in[9];
    const void* Wattn  = d_in[10];
    const void* rela   = d_in[11];
    const void* w1     = d_in[12];
    const void* b1     = d_in[13];
    const void* w2     = d_in[14];
    const void* b2     = d_in[15];

    char* ws = (char*)d_ws;
    u16*   hh     = (u16*)ws;                        // 102,400,000 B (200k x 512B combined)
    float* wrq    = (float*)(ws + 102400000);        //     409,600 B
    u32*   slots  = (u32*) (ws + 102809600);         //  12,800,000 B (200k x 16 recs)
    int*   deg    = (int*) (ws + 115609600);         //     800,000 B
    u16*   WsH    = (u16*) (ws + 116409600);
    u16*   WsL    = (u16*) (ws + 116442368);
    u16*   w1H    = (u16*) (ws + 116475136);
    u16*   w1L    = (u16*) (ws + 116507904);
    u16*   w2H    = (u16*) (ws + 116540672);
    u16*   w2L    = (u16*) (ws + 116573440);
    float* b1f    = (float*)(ws + 116606208);
    float* b2f    = (float*)(ws + 116606720);
    float* wattnf = (float*)(ws + 116607232);
    float* relaf  = (float*)(ws + 116607744);        //     102,400 B
    int*   flag   = (int*) (ws + 116710144);

    int nE = in_sizes[4] / 4;

    k_probe<<<1, 64, 0, stream>>>((const u32*)query, flag);
    hipMemsetAsync(deg, 0, (size_t)BN * 4, stream);
    k_wprep<<<294, 256, 0, stream>>>(Ws, w1, w2, b1, b2, Wattn, rela,
                                     WsH, WsL, w1H, w1L, w2H, w2L,
                                     b1f, b2f, wattnf, relaf, flag);
    k_wrq<<<Bb * Rr, 128, 0, stream>>>(Wr, Wqr, Wqrb, rela, query, wrq, flag);
    k_hs<<<BN / 64, 256, 0, stream>>>(hidden, WsH, WsL, hh, flag);
    k_scatter<<<(nE + 255) / 256, 256, 0, stream>>>(edges, slots, deg, nE);
    k_fused<<<BN / 64, 256, 0, stream>>>(slots, deg, hh, wrq, wattnf, hidden, relaf,
                                         w1H, w1L, w2H, w2L, b1f, b2f, d_out, flag);
}

// Round 12
// 671.579 us; speedup vs baseline: 1.1824x; 1.0196x over previous
//
#include <hip/hip_runtime.h>

typedef unsigned int u32;
typedef unsigned short u16;
typedef unsigned long long u64;
typedef __attribute__((ext_vector_type(8))) short bf16x8;
typedef __attribute__((ext_vector_type(4))) float f32x4;

#define Bb 4
#define Nn 50000
#define Dd 128
#define Rr 200
#define BN (Bb*Nn)
#define MAXDEG 16
#define LDW 136          // u16 row stride inside a wave slab (272 B, 16B-aligned)
#define SLAB 2176        // u16 per wave slab: 1 tile x 16 rows x 136 (hi plane only)

// ---------- scalar helpers ----------
__device__ __forceinline__ float bfs(u16 u) { return __uint_as_float(((u32)u) << 16); }
__device__ __forceinline__ float bflo(u32 u) { return __uint_as_float(u << 16); }
__device__ __forceinline__ float bfhi(u32 u) { return __uint_as_float(u & 0xffff0000u); }
__device__ __forceinline__ u16 f2bf(float f) {
    u32 x = __float_as_uint(f);
    return (u16)((x + 0x7fffu + ((x >> 16) & 1u)) >> 16);
}
template<bool BF>
__device__ __forceinline__ float ld1(const void* p, int i) {
    if (BF) return bfs(((const u16*)p)[i]);
    else    return ((const float*)p)[i];
}

// ---------- inline dtype probe: every wave computes the same flag from query[0..63] ----------
__device__ __forceinline__ bool probe_bf(const void* query) {
    int lane = threadIdx.x & 63;
    u32 w = ((const u32*)query)[lane];
    int e = (int)((w >> 7) & 0xffu);
    bool plaus = (e >= 100 && e <= 150);
    unsigned long long m = __ballot(plaus);
    return __popcll(m) >= 56;
}

// ---------- prep: split weights to bf16 hi/lo, f32 copies of small tensors ----------
__global__ __launch_bounds__(256) void k_wprep(
    const void* query,
    const void* Ws, const void* w1, const void* w2,
    const void* b1, const void* b2, const void* wattn, const void* rela,
    u16* WsH, u16* WsL, u16* w1H, u16* w1L, u16* w2H, u16* w2L,
    float* b1f, float* b2f, float* wattnf, float* relaf) {
    bool bf = probe_bf(query);
    int i = blockIdx.x * 256 + threadIdx.x;
    if (i < 16384) {
        float x = bf ? bfs(((const u16*)Ws)[i]) : ((const float*)Ws)[i];
        u16 h = f2bf(x); WsH[i] = h; WsL[i] = f2bf(x - bfs(h));
    } else if (i < 32768) {
        int j = i - 16384;
        float x = bf ? bfs(((const u16*)w1)[j]) : ((const float*)w1)[j];
        u16 h = f2bf(x); w1H[j] = h; w1L[j] = f2bf(x - bfs(h));
    } else if (i < 49152) {
        int j = i - 32768;
        float x = bf ? bfs(((const u16*)w2)[j]) : ((const float*)w2)[j];
        u16 h = f2bf(x); w2H[j] = h; w2L[j] = f2bf(x - bfs(h));
    } else if (i < 49152 + 128) {
        int j = i - 49152;
        b1f[j] = bf ? bfs(((const u16*)b1)[j]) : ((const float*)b1)[j];
    } else if (i < 49152 + 256) {
        int j = i - 49152 - 128;
        b2f[j] = bf ? bfs(((const u16*)b2)[j]) : ((const float*)b2)[j];
    } else if (i < 49152 + 384) {
        int j = i - 49152 - 256;
        wattnf[j] = bf ? bfs(((const u16*)wattn)[j]) : ((const float*)wattn)[j];
    } else if (i < 49152 + 384 + 25600) {
        int j = i - 49152 - 384;
        relaf[j] = bf ? bfs(((const u16*)rela)[j]) : ((const float*)rela)[j];
    }
}

// ---------- wrq[b*R+r][a] = Wr.rela_r + Wqr.query_b + bias (tiny, f32 VALU) ----------
template<bool BF>
__device__ __forceinline__ float dotrow1(const void* W, int row, const float* s) {
    float acc = 0.f;
    if (BF) {
        const uint4* wv = (const uint4*)((const u16*)W + row * Dd);
#pragma unroll
        for (int k = 0; k < 16; k++) {
            uint4 u = wv[k];
            acc += bflo(u.x)*s[k*8+0] + bfhi(u.x)*s[k*8+1]
                 + bflo(u.y)*s[k*8+2] + bfhi(u.y)*s[k*8+3]
                 + bflo(u.z)*s[k*8+4] + bfhi(u.z)*s[k*8+5]
                 + bflo(u.w)*s[k*8+6] + bfhi(u.w)*s[k*8+7];
        }
    } else {
        const float4* wv = (const float4*)((const float*)W + row * Dd);
#pragma unroll
        for (int k = 0; k < 32; k++) {
            float4 u = wv[k];
            acc += u.x*s[4*k] + u.y*s[4*k+1] + u.z*s[4*k+2] + u.w*s[4*k+3];
        }
    }
    return acc;
}
template<bool BF>
__device__ void k_wrq_body(const void* Wr, const void* Wqr, const void* bias,
                           const void* rela, const void* query, float* wrq, float* s) {
    int br = blockIdx.x;
    int b = br / Rr, r = br % Rr;
    int a = threadIdx.x;
    s[a]      = ld1<BF>(rela,  r * Dd + a);
    s[Dd + a] = ld1<BF>(query, b * Dd + a);
    __syncthreads();
    wrq[br * Dd + a] = ld1<BF>(bias, a) + dotrow1<BF>(Wr, a, s) + dotrow1<BF>(Wqr, a, s + Dd);
}
__global__ __launch_bounds__(128) void k_wrq(const void* Wr, const void* Wqr, const void* bias,
                                             const void* rela, const void* query, float* wrq) {
    __shared__ float s[2 * Dd];
    if (probe_bf(query)) k_wrq_body<true>(Wr, Wqr, bias, rela, query, wrq, s);
    else                 k_wrq_body<false>(Wr, Wqr, bias, rela, query, wrq, s);
}

// ---------- hs = hidden @ Ws^T via split-bf16 MFMA (wave-private slab, no barriers) ----------
template<bool BF>
__device__ void hs_body(const void* hidden, const u16* WsH, const u16* WsL, u16* hs,
                        u16* __restrict__ Smh) {
    int t = threadIdx.x, lane = t & 63;
    int m16 = lane & 15, quad = lane >> 4;
    int w = t >> 6;
    int base = blockIdx.x * 64 + w * 16;
    u16* Sml = Smh + 16 * LDW;

    if (BF) {
        const u16* src = (const u16*)hidden + (size_t)base * Dd;
#pragma unroll
        for (int j = 0; j < 4; j++) {
            int flat = j * 64 + lane;            // 256 chunks of 8 u16
            int row = flat >> 4, c8 = (flat & 15) * 8;
            uint4 v = ((const uint4*)src)[flat];
            *(uint4*)(Smh + row * LDW + c8) = v;
        }
    } else {
        const float* src = (const float*)hidden + (size_t)base * Dd;
#pragma unroll
        for (int j = 0; j < 8; j++) {
            int flat = j * 64 + lane;            // 512 float4 chunks
            int row = flat >> 5, c4 = (flat & 31) * 4;
            float4 v = ((const float4*)src)[flat];
            u16 h0 = f2bf(v.x), h1 = f2bf(v.y), h2 = f2bf(v.z), h3 = f2bf(v.w);
            ushort4 hv; hv.x = h0; hv.y = h1; hv.z = h2; hv.w = h3;
            ushort4 lv; lv.x = f2bf(v.x - bfs(h0)); lv.y = f2bf(v.y - bfs(h1));
                        lv.z = f2bf(v.z - bfs(h2)); lv.w = f2bf(v.w - bfs(h3));
            *(ushort4*)(Smh + row * LDW + c4) = hv;
            *(ushort4*)(Sml + row * LDW + c4) = lv;
        }
    }
    const u16* ph = Smh + m16 * LDW + quad * 8;
    const u16* pl = Sml + m16 * LDW + quad * 8;
    bf16x8 ah[4], al[4];
#pragma unroll
    for (int ks = 0; ks < 4; ks++) {
        ah[ks] = *(const bf16x8*)(ph + ks * 32);
        if (!BF) al[ks] = *(const bf16x8*)(pl + ks * 32);
    }
#pragma unroll
    for (int nt = 0; nt < 8; nt++) {
        int n = nt * 16 + m16;
        f32x4 acc = {0.f, 0.f, 0.f, 0.f};
#pragma unroll
        for (int ks = 0; ks < 4; ks++) {
            bf16x8 bh = *(const bf16x8*)(WsH + n * Dd + ks * 32 + quad * 8);
            acc = __builtin_amdgcn_mfma_f32_16x16x32_bf16(ah[ks], bh, acc, 0, 0, 0);
            if (!BF) {
                bf16x8 bl = *(const bf16x8*)(WsL + n * Dd + ks * 32 + quad * 8);
                acc = __builtin_amdgcn_mfma_f32_16x16x32_bf16(al[ks], bh, acc, 0, 0, 0);
                acc = __builtin_amdgcn_mfma_f32_16x16x32_bf16(ah[ks], bl, acc, 0, 0, 0);
            }
        }
#pragma unroll
        for (int r = 0; r < 4; r++)
            hs[(size_t)(base + quad * 4 + r) * Dd + n] = f2bf(acc[r]);
    }
}
__global__ __launch_bounds__(256, 4) void k_hs(const void* hidden, const u16* WsH,
                                               const u16* WsL, u16* hs, const void* query) {
    __shared__ __align__(16) u16 SL[4][2 * SLAB];   // hi+lo planes (f32 path needs lo)
    u16* slab = SL[threadIdx.x >> 6];
    if (probe_bf(query)) hs_body<true>(hidden, WsH, WsL, hs, slab);
    else                 hs_body<false>(hidden, WsH, WsL, hs, slab);
}

// ---------- fused scatter+alpha: 16 lanes per edge; writes u64 (rec | alpha) slot ----------
__global__ __launch_bounds__(256) void k_alpha(const int* __restrict__ edges,
                                               const u16* __restrict__ hs,
                                               const float* __restrict__ wrq,
                                               const float* __restrict__ wattnf,
                                               u64* __restrict__ slotsAL,
                                               int* __restrict__ deg, int nE) {
    int tid = blockIdx.x * 256 + threadIdx.x;
    int g = tid >> 4, l = tid & 15;
    if (g >= nE) return;
    int4 ed = ((const int4*)edges)[g];          // bat, sub, rel, obj
    const u16*   hp = hs  + (size_t)ed.y * Dd + l * 8;
    const float* wp = wrq + (size_t)(ed.x * Rr + ed.z) * Dd + l * 8;
    uint4  hv = *(const uint4*)hp;
    float4 w0 = *(const float4*)wp;
    float4 w1 = *(const float4*)(wp + 4);
    float4 a0 = *(const float4*)(wattnf + l * 8);
    float4 a1 = *(const float4*)(wattnf + l * 8 + 4);
    float p = fmaxf(bflo(hv.x) + w0.x, 0.f) * a0.x + fmaxf(bfhi(hv.x) + w0.y, 0.f) * a0.y
            + fmaxf(bflo(hv.y) + w0.z, 0.f) * a0.z + fmaxf(bfhi(hv.y) + w0.w, 0.f) * a0.w
            + fmaxf(bflo(hv.z) + w1.x, 0.f) * a1.x + fmaxf(bfhi(hv.z) + w1.y, 0.f) * a1.y
            + fmaxf(bflo(hv.w) + w1.z, 0.f) * a1.z + fmaxf(bfhi(hv.w) + w1.w, 0.f) * a1.w;
#pragma unroll
    for (int m = 8; m >= 1; m >>= 1) p += __shfl_xor(p, m, 16);
    if (l == 0) {
        float alpha = 1.f / (1.f + __expf(-p));
        int pos = atomicAdd(&deg[ed.w], 1);
        if (pos < MAXDEG) {
            u32 rec = (u32)ed.y | ((u32)ed.z << 18);
            slotsAL[(size_t)ed.w * MAXDEG + pos] =
                (u64)rec | ((u64)__float_as_uint(alpha) << 32);
        }
    }
}

// ---------- fused: zero-hop gather (LDS-staged slots) -> hi-only slab -> 2-layer MFMA MLP ----------
template<bool BF>
__device__ __forceinline__ void gfma(u32 rec, float al, int lane,
                                     const void* __restrict__ hidden,
                                     const float* __restrict__ relaf,
                                     float& a0, float& a1) {
    int sub = rec & 0x3FFFF, rel = (rec >> 18) & 0xFF;
    float mh0, mh1;
    if (BF) { u32 mh = ((const u32*)hidden)[(size_t)sub * 64 + lane]; mh0 = bflo(mh); mh1 = bfhi(mh); }
    else    { float2 mh = ((const float2*)hidden)[(size_t)sub * 64 + lane]; mh0 = mh.x; mh1 = mh.y; }
    float2 mr = ((const float2*)relaf)[rel * 64 + lane];
    a0 += mh0 * mr.x * al;
    a1 += mh1 * mr.y * al;
}

template<bool BF>
__device__ void fused_body(const u64* __restrict__ slotsAL, const int* __restrict__ deg,
                           const void* __restrict__ hidden, const float* __restrict__ relaf,
                           const u16* w1H, const u16* w1L, const u16* w2H, const u16* w2L,
                           const float* b1f, const float* b2f, void* out,
                           u16* __restrict__ Smh, char* __restrict__ SB) {
    int t = threadIdx.x, lane = t & 63;
    int m16 = lane & 15, quad = lane >> 4;
    int w = t >> 6;
    int base = blockIdx.x * 64 + w * 16;

    // ---- stage all 16 nodes' first-8 (rec|alpha) slots into LDS: one dwordx4/lane ----
    {
        const uint4* sp = (const uint4*)((const char*)(slotsAL + (size_t)base * MAXDEG)
                                         + (size_t)(lane >> 2) * (MAXDEG * 8) + (lane & 3) * 16);
        *(uint4*)(SB + lane * 16) = *sp;     // SB byte: node*64 + e*8 -> (rec, alpha-bits)
    }
    // same-wave RAW on LDS; compiler inserts lgkmcnt

    // ---- gather phase: node pairs, masked 4-edge groups, zero dependent hops ----
    for (int i = 0; i < 16; i += 2) {
        int nA = base + i, nB = nA + 1;
        int dA = deg[nA]; if (dA > MAXDEG) dA = MAXDEG;
        int dB = deg[nB]; if (dB > MAXDEG) dB = MAXDEG;
        const char* pA = SB + i * 64;
        const char* pB = pA + 64;
        float aA0 = 0.f, aA1 = 0.f, aB0 = 0.f, aB1 = 0.f;

        // group 1: edges 0..3 of both nodes (8 independent payload gathers)
#pragma unroll
        for (int e = 0; e < 4; e++) {
            uint2 qA = *(const uint2*)(pA + e * 8);
            uint2 qB = *(const uint2*)(pB + e * 8);
            u32  rA = (e < dA) ? qA.x : 0u;
            float lA = (e < dA) ? __uint_as_float(qA.y) : 0.f;
            u32  rB = (e < dB) ? qB.x : 0u;
            float lB = (e < dB) ? __uint_as_float(qB.y) : 0.f;
            gfma<BF>(rA, lA, lane, hidden, relaf, aA0, aA1);
            gfma<BF>(rB, lB, lane, hidden, relaf, aB0, aB1);
        }
        // group 2: edges 4..7 (skipped for most pairs; wave-uniform branch)
        if (dA > 4 || dB > 4) {
#pragma unroll
            for (int e = 4; e < 8; e++) {
                uint2 qA = *(const uint2*)(pA + e * 8);
                uint2 qB = *(const uint2*)(pB + e * 8);
                u32  rA = (e < dA) ? qA.x : 0u;
                float lA = (e < dA) ? __uint_as_float(qA.y) : 0.f;
                u32  rB = (e < dB) ? qB.x : 0u;
                float lB = (e < dB) ? __uint_as_float(qB.y) : 0.f;
                gfma<BF>(rA, lA, lane, hidden, relaf, aA0, aA1);
                gfma<BF>(rB, lB, lane, hidden, relaf, aB0, aB1);
            }
        }
        // rare tails (deg > 8) straight from global
        for (int e = 8; e < dA; e++) {
            u64 q = slotsAL[(size_t)nA * MAXDEG + e];
            gfma<BF>((u32)q, __uint_as_float((u32)(q >> 32)), lane, hidden, relaf, aA0, aA1);
        }
        for (int e = 8; e < dB; e++) {
            u64 q = slotsAL[(size_t)nB * MAXDEG + e];
            gfma<BF>((u32)q, __uint_as_float((u32)(q >> 32)), lane, hidden, relaf, aB0, aB1);
        }

        // hi-plane only (agg rounded to bf16; measured absmax unchanged R9-R11)
        u16 hA0 = f2bf(aA0), hA1 = f2bf(aA1);
        *(u32*)(Smh + i * LDW + 2 * lane) = (u32)hA0 | ((u32)hA1 << 16);
        u16 hB0 = f2bf(aB0), hB1 = f2bf(aB1);
        *(u32*)(Smh + (i + 1) * LDW + 2 * lane) = (u32)hB0 | ((u32)hB1 << 16);
    }

    // ---- layer 1: mid = agg @ W1^T + b1 (hi-only A-frags) ----
    const u16* ph = Smh + m16 * LDW + quad * 8;
    bf16x8 ah[4];
#pragma unroll
    for (int ks = 0; ks < 4; ks++)
        ah[ks] = *(const bf16x8*)(ph + ks * 32);
#pragma unroll
    for (int nt = 0; nt < 8; nt++) {
        int n = nt * 16 + m16;
        f32x4 acc = {0.f, 0.f, 0.f, 0.f};
#pragma unroll
        for (int ks = 0; ks < 4; ks++) {
            bf16x8 bh = *(const bf16x8*)(w1H + n * Dd + ks * 32 + quad * 8);
            acc = __builtin_amdgcn_mfma_f32_16x16x32_bf16(ah[ks], bh, acc, 0, 0, 0);
            if (!BF) {
                bf16x8 bl = *(const bf16x8*)(w1L + n * Dd + ks * 32 + quad * 8);
                acc = __builtin_amdgcn_mfma_f32_16x16x32_bf16(ah[ks], bl, acc, 0, 0, 0);
            }
        }
        float bv = b1f[n];
#pragma unroll
        for (int r = 0; r < 4; r++) {
            float v = acc[r] + bv;
            int row = quad * 4 + r;
            Smh[row * LDW + n] = f2bf(v);
        }
    }

    // ---- layer 2: out = relu(mid @ W2^T + b2), masked by deg ----
    bf16x8 mh[4];
#pragma unroll
    for (int ks = 0; ks < 4; ks++)
        mh[ks] = *(const bf16x8*)(ph + ks * 32);
    int dg[4];
#pragma unroll
    for (int r = 0; r < 4; r++) dg[r] = deg[base + quad * 4 + r];
#pragma unroll
    for (int nt = 0; nt < 8; nt++) {
        int n = nt * 16 + m16;
        f32x4 acc = {0.f, 0.f, 0.f, 0.f};
#pragma unroll
        for (int ks = 0; ks < 4; ks++) {
            bf16x8 bh = *(const bf16x8*)(w2H + n * Dd + ks * 32 + quad * 8);
            acc = __builtin_amdgcn_mfma_f32_16x16x32_bf16(mh[ks], bh, acc, 0, 0, 0);
            if (!BF) {
                bf16x8 bl = *(const bf16x8*)(w2L + n * Dd + ks * 32 + quad * 8);
                acc = __builtin_amdgcn_mfma_f32_16x16x32_bf16(mh[ks], bl, acc, 0, 0, 0);
            }
        }
        float bv = b2f[n];
#pragma unroll
        for (int r = 0; r < 4; r++) {
            float v = fmaxf(acc[r] + bv, 0.f);
            if (dg[r] == 0) v = 0.f;
            size_t o = (size_t)(base + quad * 4 + r) * Dd + n;
            if (BF) ((u16*)out)[o] = f2bf(v);
            else    ((float*)out)[o] = v;
        }
    }
}
__global__ __launch_bounds__(256, 6) void k_fused(const u64* slotsAL, const int* deg,
                                                  const void* hidden, const float* relaf,
                                                  const u16* w1H, const u16* w1L,
                                                  const u16* w2H, const u16* w2L,
                                                  const float* b1f, const float* b2f,
                                                  void* out, const void* query) {
    __shared__ __align__(16) u16 SL[4][SLAB];        // 17408 B (hi-only)
    __shared__ __align__(16) char SBL[4][1024];      //  4096 B -> 21504 B/block
    int w = threadIdx.x >> 6;
    if (probe_bf(query)) fused_body<true>(slotsAL, deg, hidden, relaf,
                                w1H, w1L, w2H, w2L, b1f, b2f, out, SL[w], SBL[w]);
    else                 fused_body<false>(slotsAL, deg, hidden, relaf,
                                 w1H, w1L, w2H, w2L, b1f, b2f, out, SL[w], SBL[w]);
}

extern "C" void kernel_launch(void* const* d_in, const int* in_sizes, int n_in,
                              void* d_out, int out_size, void* d_ws, size_t ws_size,
                              hipStream_t stream) {
    const void* query  = d_in[0];
    const void* hidden = d_in[3];
    const int*  edges  = (const int*)d_in[4];
    const void* Ws     = d_in[6];
    const void* Wr     = d_in[7];
    const void* Wqr    = d_in[8];
    const void* Wqrb   = d_in[9];
    const void* Wattn  = d_in[10];
    const void* rela   = d_in[11];
    const void* w1     = d_in[12];
    const void* b1     = d_in[13];
    const void* w2     = d_in[14];
    const void* b2     = d_in[15];

    char* ws = (char*)d_ws;
    u16*   hs     = (u16*)ws;                        //  51,200,000 B
    float* wrq    = (float*)(ws +  51200000);        //     409,600 B
    u64*   slotsAL= (u64*) (ws +  51609600);         //  25,600,000 B (200k x 16 x 8B)
    int*   deg    = (int*) (ws +  77209600);         //     800,000 B
    u16*   WsH    = (u16*) (ws +  78009600);
    u16*   WsL    = (u16*) (ws +  78042368);
    u16*   w1H    = (u16*) (ws +  78075136);
    u16*   w1L    = (u16*) (ws +  78107904);
    u16*   w2H    = (u16*) (ws +  78140672);
    u16*   w2L    = (u16*) (ws +  78173440);
    float* b1f    = (float*)(ws +  78206208);
    float* b2f    = (float*)(ws +  78206720);
    float* wattnf = (float*)(ws +  78207232);
    float* relaf  = (float*)(ws +  78207744);        //     102,400 B
    int*   flagUnused = (int*)(ws + 78310144);
    (void)flagUnused;

    int nE = in_sizes[4] / 4;

    hipMemsetAsync(deg, 0, (size_t)BN * 4, stream);
    k_wprep<<<294, 256, 0, stream>>>(query, Ws, w1, w2, b1, b2, Wattn, rela,
                                     WsH, WsL, w1H, w1L, w2H, w2L,
                                     b1f, b2f, wattnf, relaf);
    k_wrq<<<Bb * Rr, 128, 0, stream>>>(Wr, Wqr, Wqrb, rela, query, wrq);
    k_hs<<<BN / 64, 256, 0, stream>>>(hidden, WsH, WsL, hs, query);
    {
        long long thr = (long long)nE * 16;
        int blocks = (int)((thr + 255) / 256);
        k_alpha<<<blocks, 256, 0, stream>>>(edges, hs, wrq, wattnf, slotsAL, deg, nE);
    }
    k_fused<<<BN / 64, 256, 0, stream>>>(slotsAL, deg, hidden, relaf,
                                         w1H, w1L, w2H, w2L, b1f, b2f, d_out, query);
}

// Round 13
// 668.450 us; speedup vs baseline: 1.1880x; 1.0047x over previous
//
#include <hip/hip_runtime.h>

typedef unsigned int u32;
typedef unsigned short u16;
typedef unsigned long long u64;
typedef __attribute__((ext_vector_type(8))) short bf16x8;
typedef __attribute__((ext_vector_type(4))) float f32x4;

#define Bb 4
#define Nn 50000
#define Dd 128
#define Rr 200
#define BN (Bb*Nn)
#define MAXDEG 16
#define LDW 136          // u16 row stride inside a wave slab (272 B, 16B-aligned)
#define SLAB 2176        // u16 per wave slab: 1 tile x 16 rows x 136 (hi plane only)
#define NFBLK 3128       // k_fused grid: 8 XCD-slots x 391 (4 batches x 782 blocks)

// ---------- scalar helpers ----------
__device__ __forceinline__ float bfs(u16 u) { return __uint_as_float(((u32)u) << 16); }
__device__ __forceinline__ float bflo(u32 u) { return __uint_as_float(u << 16); }
__device__ __forceinline__ float bfhi(u32 u) { return __uint_as_float(u & 0xffff0000u); }
__device__ __forceinline__ u16 f2bf(float f) {
    u32 x = __float_as_uint(f);
    return (u16)((x + 0x7fffu + ((x >> 16) & 1u)) >> 16);
}
template<bool BF>
__device__ __forceinline__ float ld1(const void* p, int i) {
    if (BF) return bfs(((const u16*)p)[i]);
    else    return ((const float*)p)[i];
}

// ---------- inline dtype probe: every wave computes the same flag from query[0..63] ----------
__device__ __forceinline__ bool probe_bf(const void* query) {
    int lane = threadIdx.x & 63;
    u32 w = ((const u32*)query)[lane];
    int e = (int)((w >> 7) & 0xffu);
    bool plaus = (e >= 100 && e <= 150);
    unsigned long long m = __ballot(plaus);
    return __popcll(m) >= 56;
}

// ---------- prep: split weights to bf16 hi/lo, f32 copies of small tensors ----------
__global__ __launch_bounds__(256) void k_wprep(
    const void* query,
    const void* Ws, const void* w1, const void* w2,
    const void* b1, const void* b2, const void* wattn, const void* rela,
    u16* WsH, u16* WsL, u16* w1H, u16* w1L, u16* w2H, u16* w2L,
    float* b1f, float* b2f, float* wattnf, float* relaf) {
    bool bf = probe_bf(query);
    int i = blockIdx.x * 256 + threadIdx.x;
    if (i < 16384) {
        float x = bf ? bfs(((const u16*)Ws)[i]) : ((const float*)Ws)[i];
        u16 h = f2bf(x); WsH[i] = h; WsL[i] = f2bf(x - bfs(h));
    } else if (i < 32768) {
        int j = i - 16384;
        float x = bf ? bfs(((const u16*)w1)[j]) : ((const float*)w1)[j];
        u16 h = f2bf(x); w1H[j] = h; w1L[j] = f2bf(x - bfs(h));
    } else if (i < 49152) {
        int j = i - 32768;
        float x = bf ? bfs(((const u16*)w2)[j]) : ((const float*)w2)[j];
        u16 h = f2bf(x); w2H[j] = h; w2L[j] = f2bf(x - bfs(h));
    } else if (i < 49152 + 128) {
        int j = i - 49152;
        b1f[j] = bf ? bfs(((const u16*)b1)[j]) : ((const float*)b1)[j];
    } else if (i < 49152 + 256) {
        int j = i - 49152 - 128;
        b2f[j] = bf ? bfs(((const u16*)b2)[j]) : ((const float*)b2)[j];
    } else if (i < 49152 + 384) {
        int j = i - 49152 - 256;
        wattnf[j] = bf ? bfs(((const u16*)wattn)[j]) : ((const float*)wattn)[j];
    } else if (i < 49152 + 384 + 25600) {
        int j = i - 49152 - 384;
        relaf[j] = bf ? bfs(((const u16*)rela)[j]) : ((const float*)rela)[j];
    }
}

// ---------- wrq[b*R+r][a] = Wr.rela_r + Wqr.query_b + bias (tiny, f32 VALU) ----------
template<bool BF>
__device__ __forceinline__ float dotrow1(const void* W, int row, const float* s) {
    float acc = 0.f;
    if (BF) {
        const uint4* wv = (const uint4*)((const u16*)W + row * Dd);
#pragma unroll
        for (int k = 0; k < 16; k++) {
            uint4 u = wv[k];
            acc += bflo(u.x)*s[k*8+0] + bfhi(u.x)*s[k*8+1]
                 + bflo(u.y)*s[k*8+2] + bfhi(u.y)*s[k*8+3]
                 + bflo(u.z)*s[k*8+4] + bfhi(u.z)*s[k*8+5]
                 + bflo(u.w)*s[k*8+6] + bfhi(u.w)*s[k*8+7];
        }
    } else {
        const float4* wv = (const float4*)((const float*)W + row * Dd);
#pragma unroll
        for (int k = 0; k < 32; k++) {
            float4 u = wv[k];
            acc += u.x*s[4*k] + u.y*s[4*k+1] + u.z*s[4*k+2] + u.w*s[4*k+3];
        }
    }
    return acc;
}
template<bool BF>
__device__ void k_wrq_body(const void* Wr, const void* Wqr, const void* bias,
                           const void* rela, const void* query, float* wrq, float* s) {
    int br = blockIdx.x;
    int b = br / Rr, r = br % Rr;
    int a = threadIdx.x;
    s[a]      = ld1<BF>(rela,  r * Dd + a);
    s[Dd + a] = ld1<BF>(query, b * Dd + a);
    __syncthreads();
    wrq[br * Dd + a] = ld1<BF>(bias, a) + dotrow1<BF>(Wr, a, s) + dotrow1<BF>(Wqr, a, s + Dd);
}
__global__ __launch_bounds__(128) void k_wrq(const void* Wr, const void* Wqr, const void* bias,
                                             const void* rela, const void* query, float* wrq) {
    __shared__ float s[2 * Dd];
    if (probe_bf(query)) k_wrq_body<true>(Wr, Wqr, bias, rela, query, wrq, s);
    else                 k_wrq_body<false>(Wr, Wqr, bias, rela, query, wrq, s);
}

// ---------- hs = hidden @ Ws^T via split-bf16 MFMA (wave-private slab, no barriers) ----------
template<bool BF>
__device__ void hs_body(const void* hidden, const u16* WsH, const u16* WsL, u16* hs,
                        u16* __restrict__ Smh) {
    int t = threadIdx.x, lane = t & 63;
    int m16 = lane & 15, quad = lane >> 4;
    int w = t >> 6;
    int base = blockIdx.x * 64 + w * 16;
    u16* Sml = Smh + 16 * LDW;

    if (BF) {
        const u16* src = (const u16*)hidden + (size_t)base * Dd;
#pragma unroll
        for (int j = 0; j < 4; j++) {
            int flat = j * 64 + lane;            // 256 chunks of 8 u16
            int row = flat >> 4, c8 = (flat & 15) * 8;
            uint4 v = ((const uint4*)src)[flat];
            *(uint4*)(Smh + row * LDW + c8) = v;
        }
    } else {
        const float* src = (const float*)hidden + (size_t)base * Dd;
#pragma unroll
        for (int j = 0; j < 8; j++) {
            int flat = j * 64 + lane;            // 512 float4 chunks
            int row = flat >> 5, c4 = (flat & 31) * 4;
            float4 v = ((const float4*)src)[flat];
            u16 h0 = f2bf(v.x), h1 = f2bf(v.y), h2 = f2bf(v.z), h3 = f2bf(v.w);
            ushort4 hv; hv.x = h0; hv.y = h1; hv.z = h2; hv.w = h3;
            ushort4 lv; lv.x = f2bf(v.x - bfs(h0)); lv.y = f2bf(v.y - bfs(h1));
                        lv.z = f2bf(v.z - bfs(h2)); lv.w = f2bf(v.w - bfs(h3));
            *(ushort4*)(Smh + row * LDW + c4) = hv;
            *(ushort4*)(Sml + row * LDW + c4) = lv;
        }
    }
    const u16* ph = Smh + m16 * LDW + quad * 8;
    const u16* pl = Sml + m16 * LDW + quad * 8;
    bf16x8 ah[4], al[4];
#pragma unroll
    for (int ks = 0; ks < 4; ks++) {
        ah[ks] = *(const bf16x8*)(ph + ks * 32);
        if (!BF) al[ks] = *(const bf16x8*)(pl + ks * 32);
    }
#pragma unroll
    for (int nt = 0; nt < 8; nt++) {
        int n = nt * 16 + m16;
        f32x4 acc = {0.f, 0.f, 0.f, 0.f};
#pragma unroll
        for (int ks = 0; ks < 4; ks++) {
            bf16x8 bh = *(const bf16x8*)(WsH + n * Dd + ks * 32 + quad * 8);
            acc = __builtin_amdgcn_mfma_f32_16x16x32_bf16(ah[ks], bh, acc, 0, 0, 0);
            if (!BF) {
                bf16x8 bl = *(const bf16x8*)(WsL + n * Dd + ks * 32 + quad * 8);
                acc = __builtin_amdgcn_mfma_f32_16x16x32_bf16(al[ks], bh, acc, 0, 0, 0);
                acc = __builtin_amdgcn_mfma_f32_16x16x32_bf16(ah[ks], bl, acc, 0, 0, 0);
            }
        }
#pragma unroll
        for (int r = 0; r < 4; r++)
            hs[(size_t)(base + quad * 4 + r) * Dd + n] = f2bf(acc[r]);
    }
}
__global__ __launch_bounds__(256, 4) void k_hs(const void* hidden, const u16* WsH,
                                               const u16* WsL, u16* hs, const void* query) {
    __shared__ __align__(16) u16 SL[4][2 * SLAB];   // hi+lo planes (f32 path needs lo)
    u16* slab = SL[threadIdx.x >> 6];
    if (probe_bf(query)) hs_body<true>(hidden, WsH, WsL, hs, slab);
    else                 hs_body<false>(hidden, WsH, WsL, hs, slab);
}

// ---------- fused scatter+alpha: 16 lanes per edge; writes u64 (rec | alpha) slot ----------
__global__ __launch_bounds__(256) void k_alpha(const int* __restrict__ edges,
                                               const u16* __restrict__ hs,
                                               const float* __restrict__ wrq,
                                               const float* __restrict__ wattnf,
                                               u64* __restrict__ slotsAL,
                                               int* __restrict__ deg, int nE) {
    int tid = blockIdx.x * 256 + threadIdx.x;
    int g = tid >> 4, l = tid & 15;
    if (g >= nE) return;
    int4 ed = ((const int4*)edges)[g];          // bat, sub, rel, obj
    const u16*   hp = hs  + (size_t)ed.y * Dd + l * 8;
    const float* wp = wrq + (size_t)(ed.x * Rr + ed.z) * Dd + l * 8;
    uint4  hv = *(const uint4*)hp;
    float4 w0 = *(const float4*)wp;
    float4 w1 = *(const float4*)(wp + 4);
    float4 a0 = *(const float4*)(wattnf + l * 8);
    float4 a1 = *(const float4*)(wattnf + l * 8 + 4);
    float p = fmaxf(bflo(hv.x) + w0.x, 0.f) * a0.x + fmaxf(bfhi(hv.x) + w0.y, 0.f) * a0.y
            + fmaxf(bflo(hv.y) + w0.z, 0.f) * a0.z + fmaxf(bfhi(hv.y) + w0.w, 0.f) * a0.w
            + fmaxf(bflo(hv.z) + w1.x, 0.f) * a1.x + fmaxf(bfhi(hv.z) + w1.y, 0.f) * a1.y
            + fmaxf(bflo(hv.w) + w1.z, 0.f) * a1.z + fmaxf(bfhi(hv.w) + w1.w, 0.f) * a1.w;
#pragma unroll
    for (int m = 8; m >= 1; m >>= 1) p += __shfl_xor(p, m, 16);
    if (l == 0) {
        float alpha = 1.f / (1.f + __expf(-p));
        int pos = atomicAdd(&deg[ed.w], 1);
        if (pos < MAXDEG) {
            u32 rec = (u32)ed.y | ((u32)ed.z << 18);
            slotsAL[(size_t)ed.w * MAXDEG + pos] =
                (u64)rec | ((u64)__float_as_uint(alpha) << 32);
        }
    }
}

// ---------- fused: zero-hop gather (LDS-staged slots) -> hi-only slab -> 2-layer MFMA MLP ----------
template<bool BF>
__device__ __forceinline__ void gfma(u32 rec, float al, int lane,
                                     const void* __restrict__ hidden,
                                     const float* __restrict__ relaf,
                                     float& a0, float& a1) {
    int sub = rec & 0x3FFFF, rel = (rec >> 18) & 0xFF;
    float mh0, mh1;
    if (BF) { u32 mh = ((const u32*)hidden)[(size_t)sub * 64 + lane]; mh0 = bflo(mh); mh1 = bfhi(mh); }
    else    { float2 mh = ((const float2*)hidden)[(size_t)sub * 64 + lane]; mh0 = mh.x; mh1 = mh.y; }
    float2 mr = ((const float2*)relaf)[rel * 64 + lane];
    a0 += mh0 * mr.x * al;
    a1 += mh1 * mr.y * al;
}

template<bool BF>
__device__ void fused_body(const u64* __restrict__ slotsAL, const int* __restrict__ deg,
                           const void* __restrict__ hidden, const float* __restrict__ relaf,
                           const u16* w1H, const u16* w1L, const u16* w2H, const u16* w2L,
                           const float* b1f, const float* b2f, void* out,
                           u16* __restrict__ Smh, char* __restrict__ SB) {
    int t = threadIdx.x, lane = t & 63;
    int m16 = lane & 15, quad = lane >> 4;
    int w = t >> 6;

    // ---- XCD-batch swizzle: batch bb's blocks land on XCD slots {2bb, 2bb+1} ----
    // (graph is 4 disjoint per-batch components; each batch slab = 12.8MB vs 8MB of paired-XCD L2)
    int phys = blockIdx.x;
    int xcd = phys & 7, j = phys >> 3;
    int bb  = xcd >> 1;
    int ib  = (j << 1) | (xcd & 1);       // [0, 782)
    int loc = ib * 64 + w * 16;           // node offset within batch
    if (loc >= Nn) return;                // tail waves (no barriers in this kernel - safe)
    int base = bb * Nn + loc;

    // ---- stage all 16 nodes' first-8 (rec|alpha) slots into LDS: one dwordx4/lane ----
    {
        const uint4* sp = (const uint4*)((const char*)(slotsAL + (size_t)base * MAXDEG)
                                         + (size_t)(lane >> 2) * (MAXDEG * 8) + (lane & 3) * 16);
        *(uint4*)(SB + lane * 16) = *sp;     // SB byte: node*64 + e*8 -> (rec, alpha-bits)
    }
    // same-wave RAW on LDS; compiler inserts lgkmcnt

    // ---- gather phase: node pairs, masked 4-edge groups, zero dependent hops ----
    for (int i = 0; i < 16; i += 2) {
        int nA = base + i, nB = nA + 1;
        int dA = deg[nA]; if (dA > MAXDEG) dA = MAXDEG;
        int dB = deg[nB]; if (dB > MAXDEG) dB = MAXDEG;
        const char* pA = SB + i * 64;
        const char* pB = pA + 64;
        float aA0 = 0.f, aA1 = 0.f, aB0 = 0.f, aB1 = 0.f;

        // group 1: edges 0..3 of both nodes (8 independent payload gathers)
#pragma unroll
        for (int e = 0; e < 4; e++) {
            uint2 qA = *(const uint2*)(pA + e * 8);
            uint2 qB = *(const uint2*)(pB + e * 8);
            u32  rA = (e < dA) ? qA.x : 0u;
            float lA = (e < dA) ? __uint_as_float(qA.y) : 0.f;
            u32  rB = (e < dB) ? qB.x : 0u;
            float lB = (e < dB) ? __uint_as_float(qB.y) : 0.f;
            gfma<BF>(rA, lA, lane, hidden, relaf, aA0, aA1);
            gfma<BF>(rB, lB, lane, hidden, relaf, aB0, aB1);
        }
        // group 2: edges 4..7 (skipped for most pairs; wave-uniform branch)
        if (dA > 4 || dB > 4) {
#pragma unroll
            for (int e = 4; e < 8; e++) {
                uint2 qA = *(const uint2*)(pA + e * 8);
                uint2 qB = *(const uint2*)(pB + e * 8);
                u32  rA = (e < dA) ? qA.x : 0u;
                float lA = (e < dA) ? __uint_as_float(qA.y) : 0.f;
                u32  rB = (e < dB) ? qB.x : 0u;
                float lB = (e < dB) ? __uint_as_float(qB.y) : 0.f;
                gfma<BF>(rA, lA, lane, hidden, relaf, aA0, aA1);
                gfma<BF>(rB, lB, lane, hidden, relaf, aB0, aB1);
            }
        }
        // rare tails (deg > 8) straight from global
        for (int e = 8; e < dA; e++) {
            u64 q = slotsAL[(size_t)nA * MAXDEG + e];
            gfma<BF>((u32)q, __uint_as_float((u32)(q >> 32)), lane, hidden, relaf, aA0, aA1);
        }
        for (int e = 8; e < dB; e++) {
            u64 q = slotsAL[(size_t)nB * MAXDEG + e];
            gfma<BF>((u32)q, __uint_as_float((u32)(q >> 32)), lane, hidden, relaf, aB0, aB1);
        }

        // hi-plane only (agg rounded to bf16; measured absmax unchanged R9-R12)
        u16 hA0 = f2bf(aA0), hA1 = f2bf(aA1);
        *(u32*)(Smh + i * LDW + 2 * lane) = (u32)hA0 | ((u32)hA1 << 16);
        u16 hB0 = f2bf(aB0), hB1 = f2bf(aB1);
        *(u32*)(Smh + (i + 1) * LDW + 2 * lane) = (u32)hB0 | ((u32)hB1 << 16);
    }

    // ---- layer 1: mid = agg @ W1^T + b1 (hi-only A-frags) ----
    const u16* ph = Smh + m16 * LDW + quad * 8;
    bf16x8 ah[4];
#pragma unroll
    for (int ks = 0; ks < 4; ks++)
        ah[ks] = *(const bf16x8*)(ph + ks * 32);
#pragma unroll
    for (int nt = 0; nt < 8; nt++) {
        int n = nt * 16 + m16;
        f32x4 acc = {0.f, 0.f, 0.f, 0.f};
#pragma unroll
        for (int ks = 0; ks < 4; ks++) {
            bf16x8 bh = *(const bf16x8*)(w1H + n * Dd + ks * 32 + quad * 8);
            acc = __builtin_amdgcn_mfma_f32_16x16x32_bf16(ah[ks], bh, acc, 0, 0, 0);
            if (!BF) {
                bf16x8 bl = *(const bf16x8*)(w1L + n * Dd + ks * 32 + quad * 8);
                acc = __builtin_amdgcn_mfma_f32_16x16x32_bf16(ah[ks], bl, acc, 0, 0, 0);
            }
        }
        float bv = b1f[n];
#pragma unroll
        for (int r = 0; r < 4; r++) {
            float v = acc[r] + bv;
            int row = quad * 4 + r;
            Smh[row * LDW + n] = f2bf(v);
        }
    }

    // ---- layer 2: out = relu(mid @ W2^T + b2), masked by deg ----
    bf16x8 mh[4];
#pragma unroll
    for (int ks = 0; ks < 4; ks++)
        mh[ks] = *(const bf16x8*)(ph + ks * 32);
    int dg[4];
#pragma unroll
    for (int r = 0; r < 4; r++) dg[r] = deg[base + quad * 4 + r];
#pragma unroll
    for (int nt = 0; nt < 8; nt++) {
        int n = nt * 16 + m16;
        f32x4 acc = {0.f, 0.f, 0.f, 0.f};
#pragma unroll
        for (int ks = 0; ks < 4; ks++) {
            bf16x8 bh = *(const bf16x8*)(w2H + n * Dd + ks * 32 + quad * 8);
            acc = __builtin_amdgcn_mfma_f32_16x16x32_bf16(mh[ks], bh, acc, 0, 0, 0);
            if (!BF) {
                bf16x8 bl = *(const bf16x8*)(w2L + n * Dd + ks * 32 + quad * 8);
                acc = __builtin_amdgcn_mfma_f32_16x16x32_bf16(mh[ks], bl, acc, 0, 0, 0);
            }
        }
        float bv = b2f[n];
#pragma unroll
        for (int r = 0; r < 4; r++) {
            float v = fmaxf(acc[r] + bv, 0.f);
            if (dg[r] == 0) v = 0.f;
            size_t o = (size_t)(base + quad * 4 + r) * Dd + n;
            if (BF) ((u16*)out)[o] = f2bf(v);
            else    ((float*)out)[o] = v;
        }
    }
}
__global__ __launch_bounds__(256, 6) void k_fused(const u64* slotsAL, const int* deg,
                                                  const void* hidden, const float* relaf,
                                                  const u16* w1H, const u16* w1L,
                                                  const u16* w2H, const u16* w2L,
                                                  const float* b1f, const float* b2f,
                                                  void* out, const void* query) {
    __shared__ __align__(16) u16 SL[4][SLAB];        // 17408 B (hi-only)
    __shared__ __align__(16) char SBL[4][1024];      //  4096 B -> 21504 B/block
    int w = threadIdx.x >> 6;
    if (probe_bf(query)) fused_body<true>(slotsAL, deg, hidden, relaf,
                                w1H, w1L, w2H, w2L, b1f, b2f, out, SL[w], SBL[w]);
    else                 fused_body<false>(slotsAL, deg, hidden, relaf,
                                 w1H, w1L, w2H, w2L, b1f, b2f, out, SL[w], SBL[w]);
}

extern "C" void kernel_launch(void* const* d_in, const int* in_sizes, int n_in,
                              void* d_out, int out_size, void* d_ws, size_t ws_size,
                              hipStream_t stream) {
    const void* query  = d_in[0];
    const void* hidden = d_in[3];
    const int*  edges  = (const int*)d_in[4];
    const void* Ws     = d_in[6];
    const void* Wr     = d_in[7];
    const void* Wqr    = d_in[8];
    const void* Wqrb   = d_in[9];
    const void* Wattn  = d_in[10];
    const void* rela   = d_in[11];
    const void* w1     = d_in[12];
    const void* b1     = d_in[13];
    const void* w2     = d_in[14];
    const void* b2     = d_in[15];

    char* ws = (char*)d_ws;
    u16*   hs     = (u16*)ws;                        //  51,200,000 B
    float* wrq    = (float*)(ws +  51200000);        //     409,600 B
    u64*   slotsAL= (u64*) (ws +  51609600);         //  25,600,000 B (200k x 16 x 8B)
    int*   deg    = (int*) (ws +  77209600);         //     800,000 B
    u16*   WsH    = (u16*) (ws +  78009600);
    u16*   WsL    = (u16*) (ws +  78042368);
    u16*   w1H    = (u16*) (ws +  78075136);
    u16*   w1L    = (u16*) (ws +  78107904);
    u16*   w2H    = (u16*) (ws +  78140672);
    u16*   w2L    = (u16*) (ws +  78173440);
    float* b1f    = (float*)(ws +  78206208);
    float* b2f    = (float*)(ws +  78206720);
    float* wattnf = (float*)(ws +  78207232);
    float* relaf  = (float*)(ws +  78207744);        //     102,400 B
    int*   flagUnused = (int*)(ws + 78310144);
    (void)flagUnused;

    int nE = in_sizes[4] / 4;

    hipMemsetAsync(deg, 0, (size_t)BN * 4, stream);
    k_wprep<<<294, 256, 0, stream>>>(query, Ws, w1, w2, b1, b2, Wattn, rela,
                                     WsH, WsL, w1H, w1L, w2H, w2L,
                                     b1f, b2f, wattnf, relaf);
    k_wrq<<<Bb * Rr, 128, 0, stream>>>(Wr, Wqr, Wqrb, rela, query, wrq);
    k_hs<<<BN / 64, 256, 0, stream>>>(hidden, WsH, WsL, hs, query);
    {
        long long thr = (long long)nE * 16;
        int blocks = (int)((thr + 255) / 256);
        k_alpha<<<blocks, 256, 0, stream>>>(edges, hs, wrq, wattnf, slotsAL, deg, nE);
    }
    k_fused<<<NFBLK, 256, 0, stream>>>(slotsAL, deg, hidden, relaf,
                                       w1H, w1L, w2H, w2L, b1f, b2f, d_out, query);
}